// Round 17
// baseline (480.047 us; speedup 1.0000x reference)
//
#include <hip/hip_runtime.h>
#include <cstdint>

#define BB 8
#define NN 1024
#define KK 20
#define EPSV 1e-5f

typedef __attribute__((ext_vector_type(8))) short bf16x8;
typedef __attribute__((ext_vector_type(4))) float f32x4;

__device__ __forceinline__ unsigned fenc(float f) {
  unsigned u = __float_as_uint(f);
  return (u & 0x80000000u) ? ~u : (u | 0x80000000u);
}
__device__ __forceinline__ float fdec(unsigned u) {
  u = (u & 0x80000000u) ? (u & 0x7FFFFFFFu) : ~u;
  return __uint_as_float(u);
}
__device__ __forceinline__ unsigned short f2bf(float f) {
  unsigned u = __float_as_uint(f);
  unsigned r = u + 0x7FFFu + ((u >> 16) & 1u);   // RNE
  return (unsigned short)(r >> 16);
}
__device__ __forceinline__ unsigned mbcnt64(unsigned long long m) {
  unsigned r = __builtin_amdgcn_mbcnt_lo((unsigned)m, 0u);
  return __builtin_amdgcn_mbcnt_hi((unsigned)(m >> 32), r);
}
__device__ __forceinline__ void gload_lds16(const float* g, float* l) {
  __builtin_amdgcn_global_load_lds(
      (const __attribute__((address_space(1))) void*)g,
      (__attribute__((address_space(3))) void*)l, 16, 0, 0);
}

// ---- per-point squared norm: xx[b*N+n] = sum_c x[b][c][n]^2
template<int C>
__global__ __launch_bounds__(256) void xx_kernel(const float* __restrict__ x, float* __restrict__ xx) {
  int p = blockIdx.x * 256 + threadIdx.x;
  if (p >= BB * NN) return;
  int b = p >> 10, n = p & (NN - 1);
  const float* xb = x + (size_t)b * C * NN + n;
  float s = 0.f;
  #pragma unroll
  for (int c = 0; c < C; ++c) { float t = xb[(size_t)c * NN]; s = fmaf(t, t, s); }
  xx[p] = s;
}

// ---- pairwise d[i][j] = 2<xi,xj> - xx_i - xx_j (fp32 EXACT — knn selection
// must stay fp32; bf16 Gram failed round 13). 128x128 tile, 8x8/thread
// (4 ds_read_b128 per 64 FMA: LDS-pipe pressure halved vs 64x64).
// Staging via global_load_lds DOUBLE BUFFER: zero VGPR cost (round-15 spill
// impossible), loads for chunk k+1 issued before compute of chunk k,
// one barrier per chunk. LDS dest lane-linear (p*16B) by construction.
// Same ascending-c fmaf chain + epilogue -> d bit-identical (rounds 4-9 shape).
template<int C>
__global__ __launch_bounds__(256) void dist_kernel(const float* __restrict__ x, const float* __restrict__ xx,
                                                   float* __restrict__ d, int b0) {
  constexpr int CC = (C < 32) ? C : 32;
  constexpr int NI = CC * 32;               // float4 items per array per chunk
  constexpr int NU = (NI + 255) / 256;      // items per thread
  __shared__ __align__(16) float xi[2][CC][128];
  __shared__ __align__(16) float xj[2][CC][128];
  int bl = blockIdx.z, b = b0 + bl;
  int i0 = blockIdx.y * 128, j0 = blockIdx.x * 128;
  int t = threadIdx.x;
  int w = t >> 6, lane = t & 63;
  int wi = (w >> 1) * 64, wj = (w & 1) * 64;
  int li = (lane >> 3) * 8, lj = (lane & 7) * 8;
  float acc[8][8] = {};
  const float* xb = x + (size_t)b * C * NN;

  // stage chunk c0 into buffer buf (async, direct global->LDS)
  auto stage = [&](int buf, int c0) {
    float* bi = &xi[buf][0][0];
    float* bj = &xj[buf][0][0];
    #pragma unroll
    for (int u = 0; u < NU; ++u) {
      int p = u * 256 + t;
      if (p < NI) {
        gload_lds16(&xb[(size_t)(c0 + (p >> 5)) * NN + i0 + (p & 31) * 4], bi + p * 4);
        gload_lds16(&xb[(size_t)(c0 + (p >> 5)) * NN + j0 + (p & 31) * 4], bj + p * 4);
      }
    }
  };

  stage(0, 0);
  __syncthreads();                 // drains prologue loads (vmcnt(0) + barrier)
  int cur = 0;
  for (int c0 = 0; c0 < C; c0 += CC) {
    if (c0 + CC < C) stage(cur ^ 1, c0 + CC);   // async into other buffer
    #pragma unroll
    for (int cc = 0; cc < CC; ++cc) {
      float4 A0 = *reinterpret_cast<const float4*>(&xi[cur][cc][wi + li]);
      float4 A1 = *reinterpret_cast<const float4*>(&xi[cur][cc][wi + li + 4]);
      float4 B0 = *reinterpret_cast<const float4*>(&xj[cur][cc][wj + lj]);
      float4 B1 = *reinterpret_cast<const float4*>(&xj[cur][cc][wj + lj + 4]);
      float av[8] = {A0.x, A0.y, A0.z, A0.w, A1.x, A1.y, A1.z, A1.w};
      float bv[8] = {B0.x, B0.y, B0.z, B0.w, B1.x, B1.y, B1.z, B1.w};
      #pragma unroll
      for (int a = 0; a < 8; ++a)
        #pragma unroll
        for (int q = 0; q < 8; ++q)
          acc[a][q] = fmaf(av[a], bv[q], acc[a][q]);
    }
    __syncthreads();               // drains next-buffer loads; all reads of cur done
    cur ^= 1;
  }

  float xxj[8];
  #pragma unroll
  for (int q = 0; q < 8; ++q) xxj[q] = xx[b * NN + j0 + wj + lj + q];
  #pragma unroll
  for (int a = 0; a < 8; ++a) {
    int i = i0 + wi + li + a;
    float xxi = xx[b * NN + i];
    float4 o0v, o1v;
    o0v.x = 2.f * acc[a][0] - xxi - xxj[0];
    o0v.y = 2.f * acc[a][1] - xxi - xxj[1];
    o0v.z = 2.f * acc[a][2] - xxi - xxj[2];
    o0v.w = 2.f * acc[a][3] - xxi - xxj[3];
    o1v.x = 2.f * acc[a][4] - xxi - xxj[4];
    o1v.y = 2.f * acc[a][5] - xxi - xxj[5];
    o1v.z = 2.f * acc[a][6] - xxi - xxj[6];
    o1v.w = 2.f * acc[a][7] - xxi - xxj[7];
    *reinterpret_cast<float4*>(&d[((size_t)bl * NN + i) * NN + j0 + wj + lj]) = o0v;
    *reinterpret_cast<float4*>(&d[((size_t)bl * NN + i) * NN + j0 + wj + lj + 4]) = o1v;
  }
}

// ---- top-20 per row via ballot radix-select (set identical to lax.top_k)
__global__ __launch_bounds__(256) void topk_kernel(const float* __restrict__ d, int* __restrict__ idx, int b0) {
  int t = threadIdx.x;
  int wave = t >> 6, lane = t & 63;
  int bl = blockIdx.y, b = b0 + bl;
  int i = blockIdx.x * 4 + wave;
  const float* row = d + ((size_t)bl * NN + i) * NN;

  unsigned v[16];
  #pragma unroll
  for (int p = 0; p < 4; ++p) {
    float4 f = *reinterpret_cast<const float4*>(&row[p * 256 + lane * 4]);
    v[p * 4 + 0] = fenc(f.x);
    v[p * 4 + 1] = fenc(f.y);
    v[p * 4 + 2] = fenc(f.z);
    v[p * 4 + 3] = fenc(f.w);
  }

  unsigned long long lo = 0, hi = 0xFFFFFFFFull;
  while (lo < hi) {
    unsigned long long mid = lo + ((hi - lo + 1) >> 1);
    unsigned mt = (unsigned)mid;
    int c = 0;
    #pragma unroll
    for (int e = 0; e < 16; ++e)
      c += __popcll(__ballot(v[e] >= mt));
    if (c >= KK) lo = mid; else hi = mid - 1;
  }
  unsigned T = (unsigned)lo;

  int* op = idx + ((size_t)b * NN + i) * KK;
  int base = 0, n1 = 0;
  #pragma unroll
  for (int e = 0; e < 16; ++e) {
    unsigned long long mask = __ballot(v[e] > T);
    unsigned mb = mbcnt64(mask);
    if (v[e] > T) op[base + mb] = (e >> 2) * 256 + lane * 4 + (e & 3);
    base += __popcll(mask);
  }
  n1 = base;
  int need = KK - n1;
  int neq = 0;
  #pragma unroll
  for (int e = 0; e < 16; ++e) neq += __popcll(__ballot(v[e] == T));
  if (neq == need) {
    #pragma unroll
    for (int e = 0; e < 16; ++e) {
      unsigned long long mask = __ballot(v[e] == T);
      unsigned mb = mbcnt64(mask);
      if (v[e] == T) op[base + mb] = (e >> 2) * 256 + lane * 4 + (e & 3);
      base += __popcll(mask);
    }
  } else {
    unsigned taken = 0;
    for (int s = 0; s < need; ++s) {
      int jm = 1 << 30;
      #pragma unroll
      for (int e = 0; e < 16; ++e) {
        if (v[e] == T && !((taken >> e) & 1u)) {
          int j = (e >> 2) * 256 + lane * 4 + (e & 3);
          jm = jm < j ? jm : j;
        }
      }
      #pragma unroll
      for (int st = 1; st < 64; st <<= 1) {
        int oj = __shfl_xor(jm, st);
        jm = jm < oj ? jm : oj;
      }
      if (lane == ((jm >> 2) & 63)) {
        int e = (((jm >> 8) << 2) | (jm & 3));
        taken |= 1u << e;
        op[base + s] = jm;
      }
    }
  }
}

// ---- P_lo/P_hi fp32 GEMM (levels 1-3; outputs feed later knn, keep fp32)
template<int C, int O>
__global__ __launch_bounds__(256) void pgemm_kernel(const float* __restrict__ x, const float* __restrict__ W,
                                                    float* __restrict__ Plo, float* __restrict__ Phi) {
  constexpr int CC = (C < 64) ? C : 64;
  __shared__ __align__(16) float xs[CC][64];
  __shared__ __align__(16) float wls[CC][68];
  __shared__ __align__(16) float whs[CC][68];
  int b = blockIdx.z;
  int o0 = blockIdx.y * 64, n0 = blockIdx.x * 64;
  int t = threadIdx.x;
  int tn = t & 15, to = t >> 4;
  float accl[4][4] = {}, acch[4][4] = {};
  const float* xb = x + (size_t)b * C * NN;
  for (int c0 = 0; c0 < C; c0 += CC) {
    __syncthreads();
    for (int p = t; p < CC * 64; p += 256) {
      int cc = p >> 6, col = p & 63;
      xs[cc][col] = xb[(size_t)(c0 + cc) * NN + n0 + col];
    }
    for (int p = t; p < 64 * CC; p += 256) {
      int ol = p / CC, cc = p % CC;
      wls[cc][ol] = W[(size_t)(o0 + ol) * (2 * C) + c0 + cc];
      whs[cc][ol] = W[(size_t)(o0 + ol) * (2 * C) + C + c0 + cc];
    }
    __syncthreads();
    #pragma unroll
    for (int cc = 0; cc < CC; ++cc) {
      float4 X  = *reinterpret_cast<const float4*>(&xs[cc][tn * 4]);
      float4 Wl = *reinterpret_cast<const float4*>(&wls[cc][to * 4]);
      float4 Wh = *reinterpret_cast<const float4*>(&whs[cc][to * 4]);
      float xv[4] = {X.x, X.y, X.z, X.w};
      float wl[4] = {Wl.x, Wl.y, Wl.z, Wl.w};
      float wh[4] = {Wh.x, Wh.y, Wh.z, Wh.w};
      #pragma unroll
      for (int a = 0; a < 4; ++a)
        #pragma unroll
        for (int q = 0; q < 4; ++q) {
          accl[a][q] = fmaf(wl[a], xv[q], accl[a][q]);
          acch[a][q] = fmaf(wh[a], xv[q], acch[a][q]);
        }
    }
  }
  #pragma unroll
  for (int a = 0; a < 4; ++a) {
    int o = o0 + to * 4 + a;
    size_t base = ((size_t)b * O + o) * NN + n0 + tn * 4;
    float4 vl = {accl[a][0], accl[a][1], accl[a][2], accl[a][3]};
    float4 vh = {acch[a][0], acch[a][1], acch[a][2], acch[a][3]};
    *reinterpret_cast<float4*>(&Plo[base]) = vl;
    *reinterpret_cast<float4*>(&Phi[base]) = vh;
  }
}

// ---- edge max (levels 1-3): o-major Plo/Phi, LDS row staging
__global__ __launch_bounds__(256) void edgemax_kernel(const float* __restrict__ Plo, const float* __restrict__ Phi,
    const int* __restrict__ idx, const float* __restrict__ g, const float* __restrict__ bt,
    const float* __restrict__ m, const float* __restrict__ v,
    float* __restrict__ xout, int O) {
  __shared__ __align__(16) float srow[2][NN];
  __shared__ __align__(16) float sphi[2][64];
  __shared__ int   sidx[64 * KK];
  __shared__ float sinv[32], ssb[32];
  int b = blockIdx.z, n0 = blockIdx.y * 64, o0 = blockIdx.x * 32;
  int t = threadIdx.x;
  if (t < 32) {
    float inv = g[o0 + t] / sqrtf(v[o0 + t] + EPSV);
    sinv[t] = inv; ssb[t] = bt[o0 + t] - m[o0 + t] * inv;
  }
  for (int p = t; p < 64 * KK; p += 256) sidx[p] = idx[((size_t)b * NN + n0) * KK + p];
  const float* plobase = Plo + (size_t)b * O * NN;
  const float* phibase = Phi + (size_t)b * O * NN;
  float4 cur0 = *reinterpret_cast<const float4*>(&plobase[(size_t)(o0 + 0) * NN + t * 4]);
  float4 cur1 = *reinterpret_cast<const float4*>(&plobase[(size_t)(o0 + 1) * NN + t * 4]);
  float4 curphi;
  if (t < 32) curphi = *reinterpret_cast<const float4*>(&phibase[(size_t)(o0 + (t >> 4)) * NN + n0 + (t & 15) * 4]);
  __syncthreads();
  int n = t >> 2, kg = t & 3;
  int j0 = sidx[n * KK + kg * 5 + 0];
  int j1 = sidx[n * KK + kg * 5 + 1];
  int j2 = sidx[n * KK + kg * 5 + 2];
  int j3 = sidx[n * KK + kg * 5 + 3];
  int j4 = sidx[n * KK + kg * 5 + 4];
  for (int oo = 0; oo < 32; oo += 2) {
    *reinterpret_cast<float4*>(&srow[0][t * 4]) = cur0;
    *reinterpret_cast<float4*>(&srow[1][t * 4]) = cur1;
    if (t < 32) *reinterpret_cast<float4*>(&sphi[t >> 4][(t & 15) * 4]) = curphi;
    if (oo < 30) {
      cur0 = *reinterpret_cast<const float4*>(&plobase[(size_t)(o0 + oo + 2) * NN + t * 4]);
      cur1 = *reinterpret_cast<const float4*>(&plobase[(size_t)(o0 + oo + 3) * NN + t * 4]);
      if (t < 32) curphi = *reinterpret_cast<const float4*>(&phibase[(size_t)(o0 + oo + 2 + (t >> 4)) * NN + n0 + (t & 15) * 4]);
    }
    __syncthreads();
    float mx0 = srow[0][j0];
    mx0 = fmaxf(mx0, srow[0][j1]);
    mx0 = fmaxf(mx0, srow[0][j2]);
    mx0 = fmaxf(mx0, srow[0][j3]);
    mx0 = fmaxf(mx0, srow[0][j4]);
    float mx1 = srow[1][j0];
    mx1 = fmaxf(mx1, srow[1][j1]);
    mx1 = fmaxf(mx1, srow[1][j2]);
    mx1 = fmaxf(mx1, srow[1][j3]);
    mx1 = fmaxf(mx1, srow[1][j4]);
    mx0 = fmaxf(mx0, __shfl_xor(mx0, 1));
    mx0 = fmaxf(mx0, __shfl_xor(mx0, 2));
    mx1 = fmaxf(mx1, __shfl_xor(mx1, 1));
    mx1 = fmaxf(mx1, __shfl_xor(mx1, 2));
    if (kg == 0) {
      float z0 = mx0 - srow[0][n0 + n] + sphi[0][n];
      float z1 = mx1 - srow[1][n0 + n] + sphi[1][n];
      xout[((size_t)b * O + o0 + oo) * NN + n0 + n]     = fmaxf(fmaf(z0, sinv[oo],     ssb[oo]),     0.f);
      xout[((size_t)b * O + o0 + oo + 1) * NN + n0 + n] = fmaxf(fmaf(z1, sinv[oo + 1], ssb[oo + 1]), 0.f);
    }
    __syncthreads();
  }
}

// ---- transpose+cvt: src fp32 [b][Csrc][NN] -> dst bf16 Xb[b][NN][512] at col c0
__global__ __launch_bounds__(256) void tcvt_kernel(const float* __restrict__ src,
    unsigned short* __restrict__ dst, int Csrc, int c0) {
  __shared__ float tile[64][65];
  int b = blockIdx.z, cb = blockIdx.y * 64, n0 = blockIdx.x * 64;
  int t = threadIdx.x;
  const float* s = src + ((size_t)b * Csrc + cb) * NN + n0;
  #pragma unroll
  for (int rr = 0; rr < 4; ++rr) {
    int r = (t >> 4) + rr * 16;
    float4 v = *reinterpret_cast<const float4*>(&s[(size_t)r * NN + (t & 15) * 4]);
    tile[r][(t & 15) * 4 + 0] = v.x;
    tile[r][(t & 15) * 4 + 1] = v.y;
    tile[r][(t & 15) * 4 + 2] = v.z;
    tile[r][(t & 15) * 4 + 3] = v.w;
  }
  __syncthreads();
  #pragma unroll
  for (int rr = 0; rr < 2; ++rr) {
    int chunk = t + 256 * rr;
    int n = chunk >> 3, cg = (chunk & 7) * 8;
    unsigned short u[8];
    #pragma unroll
    for (int j = 0; j < 8; ++j) u[j] = f2bf(tile[cg + j][n]);
    *reinterpret_cast<uint4*>(&dst[((size_t)b * NN + n0 + n) * 512 + c0 + cb + cg]) =
      *reinterpret_cast<const uint4*>(u);
  }
}

// ---- fp32 -> bf16 elementwise (weights)
__global__ __launch_bounds__(256) void cvtw_kernel(const float* __restrict__ W, unsigned short* __restrict__ Wb) {
  int p = (blockIdx.x * 256 + threadIdx.x) * 4;
  float4 v = *reinterpret_cast<const float4*>(&W[p]);
  unsigned short u[4] = {f2bf(v.x), f2bf(v.y), f2bf(v.z), f2bf(v.w)};
  *reinterpret_cast<uint2*>(&Wb[p]) = *reinterpret_cast<const uint2*>(u);
}

// ---- pgemm L4 via MFMA bf16, SWAPPED operands; n-major Plo_t/Phi_t output
__global__ __launch_bounds__(256) void pgemm4_mfma_kernel(const unsigned short* __restrict__ Xb,
    const unsigned short* __restrict__ W4b, float* __restrict__ Plo_t, float* __restrict__ Phi_t) {
  int b = blockIdx.z;
  int n0 = blockIdx.x * 128, o0 = blockIdx.y * 64;
  int t = threadIdx.x, lane = t & 63, w = t >> 6;
  int r = lane & 15, kc = lane >> 4;
  const unsigned short* A  = Xb + ((size_t)b * NN + n0 + w * 32 + r) * 512 + 128 + kc * 8;
  const unsigned short* Bw = W4b + ((size_t)(o0 + r)) * 256 + kc * 8;
  f32x4 accl0[4] = {}, accl1[4] = {}, acch0[4] = {}, acch1[4] = {};
  #pragma unroll
  for (int ks = 0; ks < 128; ks += 32) {
    bf16x8 a0 = *reinterpret_cast<const bf16x8*>(A + ks);
    bf16x8 a1 = *reinterpret_cast<const bf16x8*>(A + 16 * 512 + ks);
    #pragma unroll
    for (int j = 0; j < 4; ++j) {
      bf16x8 bl = *reinterpret_cast<const bf16x8*>(Bw + (size_t)j * 16 * 256 + ks);
      bf16x8 bh = *reinterpret_cast<const bf16x8*>(Bw + (size_t)j * 16 * 256 + 128 + ks);
      accl0[j] = __builtin_amdgcn_mfma_f32_16x16x32_bf16(a0, bl, accl0[j], 0, 0, 0);
      accl1[j] = __builtin_amdgcn_mfma_f32_16x16x32_bf16(a1, bl, accl1[j], 0, 0, 0);
      acch0[j] = __builtin_amdgcn_mfma_f32_16x16x32_bf16(a0, bh, acch0[j], 0, 0, 0);
      acch1[j] = __builtin_amdgcn_mfma_f32_16x16x32_bf16(a1, bh, acch1[j], 0, 0, 0);
    }
  }
  #pragma unroll
  for (int j = 0; j < 4; ++j) {
    #pragma unroll
    for (int reg = 0; reg < 4; ++reg) {
      size_t n_a = (size_t)b * NN + n0 + w * 32 + kc * 4 + reg;
      size_t n_b = n_a + 16;
      int oc = o0 + j * 16 + r;
      Plo_t[n_a * 256 + oc] = accl0[j][reg];
      Plo_t[n_b * 256 + oc] = accl1[j][reg];
      Phi_t[n_a * 256 + oc] = acch0[j][reg];
      Phi_t[n_b * 256 + oc] = acch1[j][reg];
    }
  }
}

// ---- edge max L4 (n-major): zero LDS/barriers, coalesced gathers, bf16 out
__global__ __launch_bounds__(256) void edgemax4_kernel(const float* __restrict__ Plo_t,
    const float* __restrict__ Phi_t, const int* __restrict__ idx,
    const float* __restrict__ g, const float* __restrict__ bt,
    const float* __restrict__ m, const float* __restrict__ v,
    unsigned short* __restrict__ Xb) {
  int b = blockIdx.y, t = threadIdx.x;
  int n = blockIdx.x * 4 + (t >> 6);
  int oc = (t & 63) * 4;
  const int* ip = idx + ((size_t)b * NN + n) * KK;
  const float* base = Plo_t + (size_t)b * NN * 256;
  float4 mx = {-3.4e38f, -3.4e38f, -3.4e38f, -3.4e38f};
  #pragma unroll
  for (int k = 0; k < KK; ++k) {
    float4 vv = *reinterpret_cast<const float4*>(base + (size_t)ip[k] * 256 + oc);
    mx.x = fmaxf(mx.x, vv.x);
    mx.y = fmaxf(mx.y, vv.y);
    mx.z = fmaxf(mx.z, vv.z);
    mx.w = fmaxf(mx.w, vv.w);
  }
  float4 self = *reinterpret_cast<const float4*>(base + (size_t)n * 256 + oc);
  float4 ph = *reinterpret_cast<const float4*>(Phi_t + ((size_t)b * NN + n) * 256 + oc);
  float4 gg = *reinterpret_cast<const float4*>(g + oc);
  float4 bb = *reinterpret_cast<const float4*>(bt + oc);
  float4 mm = *reinterpret_cast<const float4*>(m + oc);
  float4 vv4 = *reinterpret_cast<const float4*>(v + oc);
  float mxa[4] = {mx.x, mx.y, mx.z, mx.w};
  float sfa[4] = {self.x, self.y, self.z, self.w};
  float pha[4] = {ph.x, ph.y, ph.z, ph.w};
  float ga[4] = {gg.x, gg.y, gg.z, gg.w};
  float ba[4] = {bb.x, bb.y, bb.z, bb.w};
  float ma[4] = {mm.x, mm.y, mm.z, mm.w};
  float va[4] = {vv4.x, vv4.y, vv4.z, vv4.w};
  unsigned short u[4];
  #pragma unroll
  for (int e = 0; e < 4; ++e) {
    float inv = ga[e] / sqrtf(va[e] + EPSV);
    float z = mxa[e] - sfa[e] + pha[e];
    float y = fmaxf(fmaf(z, inv, ba[e] - ma[e] * inv), 0.f);
    u[e] = f2bf(y);
  }
  *reinterpret_cast<uint2*>(&Xb[((size_t)b * NN + n) * 512 + 256 + oc]) =
    *reinterpret_cast<const uint2*>(u);
}

// ---- conv5 via MFMA bf16: A (W-tile) in LDS fragment-major, B in registers
__global__ __launch_bounds__(256, 1) void conv5_mfma_kernel(const unsigned short* __restrict__ Xb,
    const unsigned short* __restrict__ W5b, unsigned* __restrict__ henc) {
  __shared__ __align__(16) unsigned short lA[4096 * 8];
  int b = blockIdx.z;
  int n0 = blockIdx.x * 128, o0 = blockIdx.y * 64;
  int t = threadIdx.x, lane = t & 63, w = t >> 6;
  int r = lane & 15, kc = lane >> 4;

  const unsigned short* B = Xb + ((size_t)b * NN + n0 + w * 32 + r) * 512 + kc * 8;
  bf16x8 b0[16], b1[16];
  #pragma unroll
  for (int ks = 0; ks < 16; ++ks) {
    b0[ks] = *reinterpret_cast<const bf16x8*>(B + ks * 32);
    b1[ks] = *reinterpret_cast<const bf16x8*>(B + 16 * 512 + ks * 32);
  }

  #pragma unroll
  for (int i = 0; i < 16; ++i) {
    int e = i * 256 + t;
    int le = e & 63, je = (e >> 6) & 3, kse = e >> 8;
    const unsigned short* src = W5b + ((size_t)(o0 + je * 16 + (le & 15))) * 512 + ((le >> 4) & 3) * 8 + kse * 32;
    *reinterpret_cast<uint4*>(&lA[(size_t)e * 8]) = *reinterpret_cast<const uint4*>(src);
  }
  __syncthreads();

  f32x4 acc00 = {}, acc01 = {}, acc10 = {}, acc11 = {};
  f32x4 acc20 = {}, acc21 = {}, acc30 = {}, acc31 = {};
  #pragma unroll
  for (int ks = 0; ks < 16; ++ks) {
    bf16x8 a0 = *reinterpret_cast<const bf16x8*>(&lA[(size_t)((ks * 4 + 0) * 64 + lane) * 8]);
    bf16x8 a1 = *reinterpret_cast<const bf16x8*>(&lA[(size_t)((ks * 4 + 1) * 64 + lane) * 8]);
    bf16x8 a2 = *reinterpret_cast<const bf16x8*>(&lA[(size_t)((ks * 4 + 2) * 64 + lane) * 8]);
    bf16x8 a3 = *reinterpret_cast<const bf16x8*>(&lA[(size_t)((ks * 4 + 3) * 64 + lane) * 8]);
    acc00 = __builtin_amdgcn_mfma_f32_16x16x32_bf16(a0, b0[ks], acc00, 0, 0, 0);
    acc01 = __builtin_amdgcn_mfma_f32_16x16x32_bf16(a0, b1[ks], acc01, 0, 0, 0);
    acc10 = __builtin_amdgcn_mfma_f32_16x16x32_bf16(a1, b0[ks], acc10, 0, 0, 0);
    acc11 = __builtin_amdgcn_mfma_f32_16x16x32_bf16(a1, b1[ks], acc11, 0, 0, 0);
    acc20 = __builtin_amdgcn_mfma_f32_16x16x32_bf16(a2, b0[ks], acc20, 0, 0, 0);
    acc21 = __builtin_amdgcn_mfma_f32_16x16x32_bf16(a2, b1[ks], acc21, 0, 0, 0);
    acc30 = __builtin_amdgcn_mfma_f32_16x16x32_bf16(a3, b0[ks], acc30, 0, 0, 0);
    acc31 = __builtin_amdgcn_mfma_f32_16x16x32_bf16(a3, b1[ks], acc31, 0, 0, 0);
  }

  f32x4 m0 = {fmaxf(acc00[0], acc01[0]), fmaxf(acc00[1], acc01[1]),
              fmaxf(acc00[2], acc01[2]), fmaxf(acc00[3], acc01[3])};
  f32x4 m1 = {fmaxf(acc10[0], acc11[0]), fmaxf(acc10[1], acc11[1]),
              fmaxf(acc10[2], acc11[2]), fmaxf(acc10[3], acc11[3])};
  f32x4 m2 = {fmaxf(acc20[0], acc21[0]), fmaxf(acc20[1], acc21[1]),
              fmaxf(acc20[2], acc21[2]), fmaxf(acc20[3], acc21[3])};
  f32x4 m3 = {fmaxf(acc30[0], acc31[0]), fmaxf(acc30[1], acc31[1]),
              fmaxf(acc30[2], acc31[2]), fmaxf(acc30[3], acc31[3])};
  #pragma unroll
  for (int st = 1; st < 16; st <<= 1) {
    #pragma unroll
    for (int reg = 0; reg < 4; ++reg) {
      m0[reg] = fmaxf(m0[reg], __shfl_xor(m0[reg], st));
      m1[reg] = fmaxf(m1[reg], __shfl_xor(m1[reg], st));
      m2[reg] = fmaxf(m2[reg], __shfl_xor(m2[reg], st));
      m3[reg] = fmaxf(m3[reg], __shfl_xor(m3[reg], st));
    }
  }
  if (r == 0) {
    #pragma unroll
    for (int reg = 0; reg < 4; ++reg) {
      atomicMax(&henc[b * 1024 + o0 + 0 * 16 + kc * 4 + reg], fenc(m0[reg]));
      atomicMax(&henc[b * 1024 + o0 + 1 * 16 + kc * 4 + reg], fenc(m1[reg]));
      atomicMax(&henc[b * 1024 + o0 + 2 * 16 + kc * 4 + reg], fenc(m2[reg]));
      atomicMax(&henc[b * 1024 + o0 + 3 * 16 + kc * 4 + reg], fenc(m3[reg]));
    }
  }
}

// ---- FC1
__global__ __launch_bounds__(256) void fc1_kernel(
    const unsigned* __restrict__ henc,
    const float* __restrict__ g5, const float* __restrict__ b5, const float* __restrict__ m5, const float* __restrict__ v5,
    const float* __restrict__ L1W,
    const float* __restrict__ g6, const float* __restrict__ b6, const float* __restrict__ m6, const float* __restrict__ v6,
    float* __restrict__ y1) {
  __shared__ float sh[1024];
  int b = blockIdx.y, t = threadIdx.x;
  int o0 = blockIdx.x * 64;
  for (int o = t; o < 1024; o += 256) {
    float f = fdec(henc[b * 1024 + o]);
    float inv = g5[o] / sqrtf(v5[o] + EPSV);
    sh[o] = fmaxf(fmaf(f, inv, b5[o] - m5[o] * inv), 0.f);
  }
  __syncthreads();
  int o = o0 + (t >> 2), part = t & 3;
  float acc = 0.f;
  const float4* w4 = reinterpret_cast<const float4*>(L1W + (size_t)o * 1024 + part * 256);
  const float4* h4 = reinterpret_cast<const float4*>(sh + part * 256);
  #pragma unroll 8
  for (int c = 0; c < 64; ++c) {
    float4 a = w4[c], q = h4[c];
    acc = fmaf(a.x, q.x, fmaf(a.y, q.y, fmaf(a.z, q.z, fmaf(a.w, q.w, acc))));
  }
  acc += __shfl_xor(acc, 1);
  acc += __shfl_xor(acc, 2);
  if (part == 0) {
    float inv = g6[o] / sqrtf(v6[o] + EPSV);
    y1[b * 512 + o] = fmaxf(fmaf(acc, inv, b6[o] - m6[o] * inv), 0.f);
  }
}

// ---- FC2+FC3
__global__ __launch_bounds__(256) void fc2_kernel(
    const float* __restrict__ y1,
    const float* __restrict__ L2W, const float* __restrict__ L2b,
    const float* __restrict__ g7, const float* __restrict__ b7, const float* __restrict__ m7, const float* __restrict__ v7,
    const float* __restrict__ L3W, const float* __restrict__ L3b,
    float* __restrict__ out) {
  __shared__ float sy1[512];
  __shared__ float sy2[256];
  int b = blockIdx.x, t = threadIdx.x;
  for (int o = t; o < 512; o += 256) sy1[o] = y1[b * 512 + o];
  __syncthreads();
  {
    int o = t;
    float acc = L2b[o];
    const float4* w4 = reinterpret_cast<const float4*>(L2W + (size_t)o * 512);
    const float4* q4 = reinterpret_cast<const float4*>(sy1);
    for (int c = 0; c < 128; ++c) {
      float4 a = w4[c], q = q4[c];
      acc = fmaf(a.x, q.x, fmaf(a.y, q.y, fmaf(a.z, q.z, fmaf(a.w, q.w, acc))));
    }
    float inv = g7[o] / sqrtf(v7[o] + EPSV);
    sy2[o] = fmaxf(fmaf(acc, inv, b7[o] - m7[o] * inv), 0.f);
  }
  __syncthreads();
  if (t < 8) {
    float acc = L3b[t];
    const float4* w4 = reinterpret_cast<const float4*>(L3W + (size_t)t * 256);
    const float4* q4 = reinterpret_cast<const float4*>(sy2);
    for (int c = 0; c < 64; ++c) {
      float4 a = w4[c], q = q4[c];
      acc = fmaf(a.x, q.x, fmaf(a.y, q.y, fmaf(a.z, q.z, fmaf(a.w, q.w, acc))));
    }
    out[b * 8 + t] = acc;
  }
}

extern "C" void kernel_launch(void* const* d_in, const int* in_sizes, int n_in,
                              void* d_out, int out_size, void* d_ws, size_t ws_size,
                              hipStream_t stream) {
  (void)in_sizes; (void)n_in; (void)out_size;
  const float* x   = (const float*)d_in[0];
  const float* W1  = (const float*)d_in[1];
  const float* W2  = (const float*)d_in[2];
  const float* W3  = (const float*)d_in[3];
  const float* W4  = (const float*)d_in[4];
  const float* W5  = (const float*)d_in[5];
  const float* bnp[7][4];
  for (int i = 0; i < 7; ++i)
    for (int j = 0; j < 4; ++j)
      bnp[i][j] = (const float*)d_in[6 + i * 4 + j];
  const float* L1W = (const float*)d_in[34];
  const float* L2W = (const float*)d_in[35];
  const float* L2b = (const float*)d_in[36];
  const float* L3W = (const float*)d_in[37];
  const float* L3b = (const float*)d_in[38];
  float* out = (float*)d_out;

  char* wsb = (char*)d_ws;
  size_t off = 0;
  auto alloc = [&](size_t bytes) -> void* {
    void* p = wsb + off; off += (bytes + 255) & ~(size_t)255; return p;
  };
  int*      idx  = (int*)     alloc((size_t)BB * NN * KK * 4);
  float*    xx   = (float*)   alloc((size_t)BB * NN * 4);
  float*    x1   = (float*)   alloc((size_t)BB * 64  * NN * 4);
  float*    x2   = (float*)   alloc((size_t)BB * 64  * NN * 4);
  float*    x3   = (float*)   alloc((size_t)BB * 128 * NN * 4);
  float*    Plo  = (float*)   alloc((size_t)BB * 256 * NN * 4);
  float*    Phi  = (float*)   alloc((size_t)BB * 256 * NN * 4);
  unsigned* henc = (unsigned*)alloc((size_t)BB * 1024 * 4);
  float*    y1   = (float*)   alloc((size_t)BB * 512 * 4);
  unsigned short* Xb  = (unsigned short*)alloc((size_t)BB * NN * 512 * 2);
  unsigned short* W5b = (unsigned short*)alloc((size_t)1024 * 512 * 2);
  unsigned short* W4b = (unsigned short*)alloc((size_t)256 * 256 * 2);
  size_t left = (ws_size > off) ? (ws_size - off) : 0;
  int nb = 8;
  while (nb > 1 && (size_t)nb * NN * NN * 4 > left) nb >>= 1;
  float* dbuf = (float*)(wsb + off);

  dim3 thr(256);
  #define KNN_PHASE(CIN, XIN)                                                              \
    xx_kernel<CIN><<<dim3(32), thr, 0, stream>>>(XIN, xx);                                 \
    for (int b0 = 0; b0 < BB; b0 += nb) {                                                  \
      dist_kernel<CIN><<<dim3(8, 8, nb), thr, 0, stream>>>(XIN, xx, dbuf, b0);             \
      topk_kernel<<<dim3(NN / 4, nb), thr, 0, stream>>>(dbuf, idx, b0);                    \
    }

  cvtw_kernel<<<dim3(512), thr, 0, stream>>>(W5, W5b);
  cvtw_kernel<<<dim3(64), thr, 0, stream>>>(W4, W4b);

  // ---- level 1: x (C=4) -> x1 (O=64)
  KNN_PHASE(4, x)
  pgemm_kernel<4, 64><<<dim3(16, 1, BB), thr, 0, stream>>>(x, W1, Plo, Phi);
  edgemax_kernel<<<dim3(2, 16, BB), thr, 0, stream>>>(Plo, Phi, idx,
      bnp[0][0], bnp[0][1], bnp[0][2], bnp[0][3], x1, 64);
  tcvt_kernel<<<dim3(16, 1, BB), thr, 0, stream>>>(x1, Xb, 64, 0);
  // ---- level 2: x1 (C=64) -> x2 (O=64)
  KNN_PHASE(64, x1)
  pgemm_kernel<64, 64><<<dim3(16, 1, BB), thr, 0, stream>>>(x1, W2, Plo, Phi);
  edgemax_kernel<<<dim3(2, 16, BB), thr, 0, stream>>>(Plo, Phi, idx,
      bnp[1][0], bnp[1][1], bnp[1][2], bnp[1][3], x2, 64);
  tcvt_kernel<<<dim3(16, 1, BB), thr, 0, stream>>>(x2, Xb, 64, 64);
  // ---- level 3: x2 (C=64) -> x3 (O=128)
  KNN_PHASE(64, x2)
  pgemm_kernel<64, 128><<<dim3(16, 2, BB), thr, 0, stream>>>(x2, W3, Plo, Phi);
  edgemax_kernel<<<dim3(4, 16, BB), thr, 0, stream>>>(Plo, Phi, idx,
      bnp[2][0], bnp[2][1], bnp[2][2], bnp[2][3], x3, 128);
  tcvt_kernel<<<dim3(16, 2, BB), thr, 0, stream>>>(x3, Xb, 128, 128);
  // ---- level 4 (last knn level -> bf16 MFMA end-to-end, n-major)
  KNN_PHASE(128, x3)
  pgemm4_mfma_kernel<<<dim3(8, 4, BB), thr, 0, stream>>>(Xb, W4b, Plo, Phi);
  edgemax4_kernel<<<dim3(256, BB), thr, 0, stream>>>(Plo, Phi, idx,
      bnp[3][0], bnp[3][1], bnp[3][2], bnp[3][3], Xb);
  #undef KNN_PHASE

  // ---- conv5 (MFMA bf16) + global max-pool
  hipMemsetAsync(henc, 0, (size_t)BB * 1024 * 4, stream);
  conv5_mfma_kernel<<<dim3(8, 16, BB), thr, 0, stream>>>(Xb, W5b, henc);

  // ---- FC head
  fc1_kernel<<<dim3(8, BB), thr, 0, stream>>>(henc,
      bnp[4][0], bnp[4][1], bnp[4][2], bnp[4][3], L1W,
      bnp[5][0], bnp[5][1], bnp[5][2], bnp[5][3], y1);
  fc2_kernel<<<dim3(BB), thr, 0, stream>>>(y1,
      L2W, L2b, bnp[6][0], bnp[6][1], bnp[6][2], bnp[6][3], L3W, L3b, out);
}

// Round 18
// 416.453 us; speedup vs baseline: 1.1527x; 1.1527x over previous
//
#include <hip/hip_runtime.h>
#include <cstdint>

#define BB 8
#define NN 1024
#define KK 20
#define EPSV 1e-5f

typedef __attribute__((ext_vector_type(8))) short bf16x8;
typedef __attribute__((ext_vector_type(4))) float f32x4;

__device__ __forceinline__ unsigned fenc(float f) {
  unsigned u = __float_as_uint(f);
  return (u & 0x80000000u) ? ~u : (u | 0x80000000u);
}
__device__ __forceinline__ float fdec(unsigned u) {
  u = (u & 0x80000000u) ? (u & 0x7FFFFFFFu) : ~u;
  return __uint_as_float(u);
}
__device__ __forceinline__ unsigned short f2bf(float f) {
  unsigned u = __float_as_uint(f);
  unsigned r = u + 0x7FFFu + ((u >> 16) & 1u);   // RNE
  return (unsigned short)(r >> 16);
}
__device__ __forceinline__ unsigned mbcnt64(unsigned long long m) {
  unsigned r = __builtin_amdgcn_mbcnt_lo((unsigned)m, 0u);
  return __builtin_amdgcn_mbcnt_hi((unsigned)(m >> 32), r);
}

// ---- per-point squared norm: xx[b*N+n] = sum_c x[b][c][n]^2
template<int C>
__global__ __launch_bounds__(256) void xx_kernel(const float* __restrict__ x, float* __restrict__ xx) {
  int p = blockIdx.x * 256 + threadIdx.x;
  if (p >= BB * NN) return;
  int b = p >> 10, n = p & (NN - 1);
  const float* xb = x + (size_t)b * C * NN + n;
  float s = 0.f;
  #pragma unroll
  for (int c = 0; c < C; ++c) { float t = xb[(size_t)c * NN]; s = fmaf(t, t, s); }
  xx[p] = s;
}

// ---- pairwise d[i][j] = 2<xi,xj> - xx_i - xx_j (fp32 EXACT; round-12 config:
// 64x64 tiles, CC=32 -> 16KB LDS, 2048 blocks/dispatch = 8 blocks/CU.
// Measured at its LDS-pipe ceiling (VALUBusy 35.6% vs ~33% analytic).
// Round-15 lesson: no reg-prefetch across barriers (spill). Round-17 lesson:
// no 64KB dbuf (occupancy collapse). Keep this form; d bit-identical.
template<int C>
__global__ __launch_bounds__(256) void dist_kernel(const float* __restrict__ x, const float* __restrict__ xx,
                                                   float* __restrict__ d, int b0) {
  constexpr int CC = (C < 32) ? C : 32;
  __shared__ __align__(16) float xi[CC][64];
  __shared__ __align__(16) float xj[CC][64];
  int bl = blockIdx.z, b = b0 + bl;
  int i0 = blockIdx.y * 64, j0 = blockIdx.x * 64;
  int t = threadIdx.x;
  int tj = t & 15, ti = t >> 4;
  float acc[4][4] = {};
  const float* xb = x + (size_t)b * C * NN;
  for (int c0 = 0; c0 < C; c0 += CC) {
    __syncthreads();
    for (int p = t; p < CC * 16; p += 256) {
      int cc = p >> 4, col = (p & 15) * 4;
      *reinterpret_cast<float4*>(&xi[cc][col]) =
        *reinterpret_cast<const float4*>(&xb[(size_t)(c0 + cc) * NN + i0 + col]);
      *reinterpret_cast<float4*>(&xj[cc][col]) =
        *reinterpret_cast<const float4*>(&xb[(size_t)(c0 + cc) * NN + j0 + col]);
    }
    __syncthreads();
    #pragma unroll
    for (int cc = 0; cc < CC; ++cc) {
      float4 A  = *reinterpret_cast<const float4*>(&xi[cc][ti * 4]);
      float4 Bv = *reinterpret_cast<const float4*>(&xj[cc][tj * 4]);
      float av[4] = {A.x, A.y, A.z, A.w};
      float bv[4] = {Bv.x, Bv.y, Bv.z, Bv.w};
      #pragma unroll
      for (int a = 0; a < 4; ++a)
        #pragma unroll
        for (int q = 0; q < 4; ++q)
          acc[a][q] = fmaf(av[a], bv[q], acc[a][q]);
    }
  }
  #pragma unroll
  for (int a = 0; a < 4; ++a) {
    int i = i0 + ti * 4 + a;
    float xxi = xx[b * NN + i];
    float4 o;
    o.x = 2.f * acc[a][0] - xxi - xx[b * NN + j0 + tj * 4 + 0];
    o.y = 2.f * acc[a][1] - xxi - xx[b * NN + j0 + tj * 4 + 1];
    o.z = 2.f * acc[a][2] - xxi - xx[b * NN + j0 + tj * 4 + 2];
    o.w = 2.f * acc[a][3] - xxi - xx[b * NN + j0 + tj * 4 + 3];
    *reinterpret_cast<float4*>(&d[((size_t)bl * NN + i) * NN + j0 + tj * 4]) = o;
  }
}

// ---- top-20 per row via ballot radix-select (set identical to lax.top_k)
__global__ __launch_bounds__(256) void topk_kernel(const float* __restrict__ d, int* __restrict__ idx, int b0) {
  int t = threadIdx.x;
  int wave = t >> 6, lane = t & 63;
  int bl = blockIdx.y, b = b0 + bl;
  int i = blockIdx.x * 4 + wave;
  const float* row = d + ((size_t)bl * NN + i) * NN;

  unsigned v[16];
  #pragma unroll
  for (int p = 0; p < 4; ++p) {
    float4 f = *reinterpret_cast<const float4*>(&row[p * 256 + lane * 4]);
    v[p * 4 + 0] = fenc(f.x);
    v[p * 4 + 1] = fenc(f.y);
    v[p * 4 + 2] = fenc(f.z);
    v[p * 4 + 3] = fenc(f.w);
  }

  unsigned long long lo = 0, hi = 0xFFFFFFFFull;
  while (lo < hi) {
    unsigned long long mid = lo + ((hi - lo + 1) >> 1);
    unsigned mt = (unsigned)mid;
    int c = 0;
    #pragma unroll
    for (int e = 0; e < 16; ++e)
      c += __popcll(__ballot(v[e] >= mt));
    if (c >= KK) lo = mid; else hi = mid - 1;
  }
  unsigned T = (unsigned)lo;

  int* op = idx + ((size_t)b * NN + i) * KK;
  int base = 0, n1 = 0;
  #pragma unroll
  for (int e = 0; e < 16; ++e) {
    unsigned long long mask = __ballot(v[e] > T);
    unsigned mb = mbcnt64(mask);
    if (v[e] > T) op[base + mb] = (e >> 2) * 256 + lane * 4 + (e & 3);
    base += __popcll(mask);
  }
  n1 = base;
  int need = KK - n1;
  int neq = 0;
  #pragma unroll
  for (int e = 0; e < 16; ++e) neq += __popcll(__ballot(v[e] == T));
  if (neq == need) {
    #pragma unroll
    for (int e = 0; e < 16; ++e) {
      unsigned long long mask = __ballot(v[e] == T);
      unsigned mb = mbcnt64(mask);
      if (v[e] == T) op[base + mb] = (e >> 2) * 256 + lane * 4 + (e & 3);
      base += __popcll(mask);
    }
  } else {
    unsigned taken = 0;
    for (int s = 0; s < need; ++s) {
      int jm = 1 << 30;
      #pragma unroll
      for (int e = 0; e < 16; ++e) {
        if (v[e] == T && !((taken >> e) & 1u)) {
          int j = (e >> 2) * 256 + lane * 4 + (e & 3);
          jm = jm < j ? jm : j;
        }
      }
      #pragma unroll
      for (int st = 1; st < 64; st <<= 1) {
        int oj = __shfl_xor(jm, st);
        jm = jm < oj ? jm : oj;
      }
      if (lane == ((jm >> 2) & 63)) {
        int e = (((jm >> 8) << 2) | (jm & 3));
        taken |= 1u << e;
        op[base + s] = jm;
      }
    }
  }
}

// ---- P_lo/P_hi fp32 GEMM (levels 1-3; outputs feed later knn, keep fp32)
template<int C, int O>
__global__ __launch_bounds__(256) void pgemm_kernel(const float* __restrict__ x, const float* __restrict__ W,
                                                    float* __restrict__ Plo, float* __restrict__ Phi) {
  constexpr int CC = (C < 64) ? C : 64;
  __shared__ __align__(16) float xs[CC][64];
  __shared__ __align__(16) float wls[CC][68];
  __shared__ __align__(16) float whs[CC][68];
  int b = blockIdx.z;
  int o0 = blockIdx.y * 64, n0 = blockIdx.x * 64;
  int t = threadIdx.x;
  int tn = t & 15, to = t >> 4;
  float accl[4][4] = {}, acch[4][4] = {};
  const float* xb = x + (size_t)b * C * NN;
  for (int c0 = 0; c0 < C; c0 += CC) {
    __syncthreads();
    for (int p = t; p < CC * 64; p += 256) {
      int cc = p >> 6, col = p & 63;
      xs[cc][col] = xb[(size_t)(c0 + cc) * NN + n0 + col];
    }
    for (int p = t; p < 64 * CC; p += 256) {
      int ol = p / CC, cc = p % CC;
      wls[cc][ol] = W[(size_t)(o0 + ol) * (2 * C) + c0 + cc];
      whs[cc][ol] = W[(size_t)(o0 + ol) * (2 * C) + C + c0 + cc];
    }
    __syncthreads();
    #pragma unroll
    for (int cc = 0; cc < CC; ++cc) {
      float4 X  = *reinterpret_cast<const float4*>(&xs[cc][tn * 4]);
      float4 Wl = *reinterpret_cast<const float4*>(&wls[cc][to * 4]);
      float4 Wh = *reinterpret_cast<const float4*>(&whs[cc][to * 4]);
      float xv[4] = {X.x, X.y, X.z, X.w};
      float wl[4] = {Wl.x, Wl.y, Wl.z, Wl.w};
      float wh[4] = {Wh.x, Wh.y, Wh.z, Wh.w};
      #pragma unroll
      for (int a = 0; a < 4; ++a)
        #pragma unroll
        for (int q = 0; q < 4; ++q) {
          accl[a][q] = fmaf(wl[a], xv[q], accl[a][q]);
          acch[a][q] = fmaf(wh[a], xv[q], acch[a][q]);
        }
    }
  }
  #pragma unroll
  for (int a = 0; a < 4; ++a) {
    int o = o0 + to * 4 + a;
    size_t base = ((size_t)b * O + o) * NN + n0 + tn * 4;
    float4 vl = {accl[a][0], accl[a][1], accl[a][2], accl[a][3]};
    float4 vh = {acch[a][0], acch[a][1], acch[a][2], acch[a][3]};
    *reinterpret_cast<float4*>(&Plo[base]) = vl;
    *reinterpret_cast<float4*>(&Phi[base]) = vh;
  }
}

// ---- edge max (levels 1-3): FOUR rows per iteration (half the barriers of
// the 2-row version; gathers/max/BN math identical -> bit-identical output).
__global__ __launch_bounds__(256) void edgemax_kernel(const float* __restrict__ Plo, const float* __restrict__ Phi,
    const int* __restrict__ idx, const float* __restrict__ g, const float* __restrict__ bt,
    const float* __restrict__ m, const float* __restrict__ v,
    float* __restrict__ xout, int O) {
  __shared__ __align__(16) float srow[4][NN];
  __shared__ __align__(16) float sphi[4][64];
  __shared__ int   sidx[64 * KK];
  __shared__ float sinv[32], ssb[32];
  int b = blockIdx.z, n0 = blockIdx.y * 64, o0 = blockIdx.x * 32;
  int t = threadIdx.x;
  if (t < 32) {
    float inv = g[o0 + t] / sqrtf(v[o0 + t] + EPSV);
    sinv[t] = inv; ssb[t] = bt[o0 + t] - m[o0 + t] * inv;
  }
  for (int p = t; p < 64 * KK; p += 256) sidx[p] = idx[((size_t)b * NN + n0) * KK + p];
  const float* plobase = Plo + (size_t)b * O * NN;
  const float* phibase = Phi + (size_t)b * O * NN;
  float4 cur0 = *reinterpret_cast<const float4*>(&plobase[(size_t)(o0 + 0) * NN + t * 4]);
  float4 cur1 = *reinterpret_cast<const float4*>(&plobase[(size_t)(o0 + 1) * NN + t * 4]);
  float4 cur2 = *reinterpret_cast<const float4*>(&plobase[(size_t)(o0 + 2) * NN + t * 4]);
  float4 cur3 = *reinterpret_cast<const float4*>(&plobase[(size_t)(o0 + 3) * NN + t * 4]);
  float4 curphi;
  if (t < 64) curphi = *reinterpret_cast<const float4*>(&phibase[(size_t)(o0 + (t >> 4)) * NN + n0 + (t & 15) * 4]);
  __syncthreads();
  int n = t >> 2, kg = t & 3;
  int j0 = sidx[n * KK + kg * 5 + 0];
  int j1 = sidx[n * KK + kg * 5 + 1];
  int j2 = sidx[n * KK + kg * 5 + 2];
  int j3 = sidx[n * KK + kg * 5 + 3];
  int j4 = sidx[n * KK + kg * 5 + 4];
  for (int oo = 0; oo < 32; oo += 4) {
    *reinterpret_cast<float4*>(&srow[0][t * 4]) = cur0;
    *reinterpret_cast<float4*>(&srow[1][t * 4]) = cur1;
    *reinterpret_cast<float4*>(&srow[2][t * 4]) = cur2;
    *reinterpret_cast<float4*>(&srow[3][t * 4]) = cur3;
    if (t < 64) *reinterpret_cast<float4*>(&sphi[t >> 4][(t & 15) * 4]) = curphi;
    if (oo < 28) {
      cur0 = *reinterpret_cast<const float4*>(&plobase[(size_t)(o0 + oo + 4) * NN + t * 4]);
      cur1 = *reinterpret_cast<const float4*>(&plobase[(size_t)(o0 + oo + 5) * NN + t * 4]);
      cur2 = *reinterpret_cast<const float4*>(&plobase[(size_t)(o0 + oo + 6) * NN + t * 4]);
      cur3 = *reinterpret_cast<const float4*>(&plobase[(size_t)(o0 + oo + 7) * NN + t * 4]);
      if (t < 64) curphi = *reinterpret_cast<const float4*>(&phibase[(size_t)(o0 + oo + 4 + (t >> 4)) * NN + n0 + (t & 15) * 4]);
    }
    __syncthreads();
    #pragma unroll
    for (int r = 0; r < 4; ++r) {
      float mx = srow[r][j0];
      mx = fmaxf(mx, srow[r][j1]);
      mx = fmaxf(mx, srow[r][j2]);
      mx = fmaxf(mx, srow[r][j3]);
      mx = fmaxf(mx, srow[r][j4]);
      mx = fmaxf(mx, __shfl_xor(mx, 1));
      mx = fmaxf(mx, __shfl_xor(mx, 2));
      if (kg == 0) {
        float z = mx - srow[r][n0 + n] + sphi[r][n];
        xout[((size_t)b * O + o0 + oo + r) * NN + n0 + n] =
          fmaxf(fmaf(z, sinv[oo + r], ssb[oo + r]), 0.f);
      }
    }
    __syncthreads();
  }
}

// ---- transpose+cvt: src fp32 [b][Csrc][NN] -> dst bf16 Xb[b][NN][512] at col c0
__global__ __launch_bounds__(256) void tcvt_kernel(const float* __restrict__ src,
    unsigned short* __restrict__ dst, int Csrc, int c0) {
  __shared__ float tile[64][65];
  int b = blockIdx.z, cb = blockIdx.y * 64, n0 = blockIdx.x * 64;
  int t = threadIdx.x;
  const float* s = src + ((size_t)b * Csrc + cb) * NN + n0;
  #pragma unroll
  for (int rr = 0; rr < 4; ++rr) {
    int r = (t >> 4) + rr * 16;
    float4 v = *reinterpret_cast<const float4*>(&s[(size_t)r * NN + (t & 15) * 4]);
    tile[r][(t & 15) * 4 + 0] = v.x;
    tile[r][(t & 15) * 4 + 1] = v.y;
    tile[r][(t & 15) * 4 + 2] = v.z;
    tile[r][(t & 15) * 4 + 3] = v.w;
  }
  __syncthreads();
  #pragma unroll
  for (int rr = 0; rr < 2; ++rr) {
    int chunk = t + 256 * rr;
    int n = chunk >> 3, cg = (chunk & 7) * 8;
    unsigned short u[8];
    #pragma unroll
    for (int j = 0; j < 8; ++j) u[j] = f2bf(tile[cg + j][n]);
    *reinterpret_cast<uint4*>(&dst[((size_t)b * NN + n0 + n) * 512 + c0 + cb + cg]) =
      *reinterpret_cast<const uint4*>(u);
  }
}

// ---- fp32 -> bf16 elementwise (weights)
__global__ __launch_bounds__(256) void cvtw_kernel(const float* __restrict__ W, unsigned short* __restrict__ Wb) {
  int p = (blockIdx.x * 256 + threadIdx.x) * 4;
  float4 v = *reinterpret_cast<const float4*>(&W[p]);
  unsigned short u[4] = {f2bf(v.x), f2bf(v.y), f2bf(v.z), f2bf(v.w)};
  *reinterpret_cast<uint2*>(&Wb[p]) = *reinterpret_cast<const uint2*>(u);
}

// ---- pgemm L4 via MFMA bf16, SWAPPED operands; n-major Plo_t/Phi_t output
__global__ __launch_bounds__(256) void pgemm4_mfma_kernel(const unsigned short* __restrict__ Xb,
    const unsigned short* __restrict__ W4b, float* __restrict__ Plo_t, float* __restrict__ Phi_t) {
  int b = blockIdx.z;
  int n0 = blockIdx.x * 128, o0 = blockIdx.y * 64;
  int t = threadIdx.x, lane = t & 63, w = t >> 6;
  int r = lane & 15, kc = lane >> 4;
  const unsigned short* A  = Xb + ((size_t)b * NN + n0 + w * 32 + r) * 512 + 128 + kc * 8;
  const unsigned short* Bw = W4b + ((size_t)(o0 + r)) * 256 + kc * 8;
  f32x4 accl0[4] = {}, accl1[4] = {}, acch0[4] = {}, acch1[4] = {};
  #pragma unroll
  for (int ks = 0; ks < 128; ks += 32) {
    bf16x8 a0 = *reinterpret_cast<const bf16x8*>(A + ks);
    bf16x8 a1 = *reinterpret_cast<const bf16x8*>(A + 16 * 512 + ks);
    #pragma unroll
    for (int j = 0; j < 4; ++j) {
      bf16x8 bl = *reinterpret_cast<const bf16x8*>(Bw + (size_t)j * 16 * 256 + ks);
      bf16x8 bh = *reinterpret_cast<const bf16x8*>(Bw + (size_t)j * 16 * 256 + 128 + ks);
      accl0[j] = __builtin_amdgcn_mfma_f32_16x16x32_bf16(a0, bl, accl0[j], 0, 0, 0);
      accl1[j] = __builtin_amdgcn_mfma_f32_16x16x32_bf16(a1, bl, accl1[j], 0, 0, 0);
      acch0[j] = __builtin_amdgcn_mfma_f32_16x16x32_bf16(a0, bh, acch0[j], 0, 0, 0);
      acch1[j] = __builtin_amdgcn_mfma_f32_16x16x32_bf16(a1, bh, acch1[j], 0, 0, 0);
    }
  }
  #pragma unroll
  for (int j = 0; j < 4; ++j) {
    #pragma unroll
    for (int reg = 0; reg < 4; ++reg) {
      size_t n_a = (size_t)b * NN + n0 + w * 32 + kc * 4 + reg;
      size_t n_b = n_a + 16;
      int oc = o0 + j * 16 + r;
      Plo_t[n_a * 256 + oc] = accl0[j][reg];
      Plo_t[n_b * 256 + oc] = accl1[j][reg];
      Phi_t[n_a * 256 + oc] = acch0[j][reg];
      Phi_t[n_b * 256 + oc] = acch1[j][reg];
    }
  }
}

// ---- edge max L4 (n-major): zero LDS/barriers, coalesced gathers, bf16 out
__global__ __launch_bounds__(256) void edgemax4_kernel(const float* __restrict__ Plo_t,
    const float* __restrict__ Phi_t, const int* __restrict__ idx,
    const float* __restrict__ g, const float* __restrict__ bt,
    const float* __restrict__ m, const float* __restrict__ v,
    unsigned short* __restrict__ Xb) {
  int b = blockIdx.y, t = threadIdx.x;
  int n = blockIdx.x * 4 + (t >> 6);
  int oc = (t & 63) * 4;
  const int* ip = idx + ((size_t)b * NN + n) * KK;
  const float* base = Plo_t + (size_t)b * NN * 256;
  float4 mx = {-3.4e38f, -3.4e38f, -3.4e38f, -3.4e38f};
  #pragma unroll
  for (int k = 0; k < KK; ++k) {
    float4 vv = *reinterpret_cast<const float4*>(base + (size_t)ip[k] * 256 + oc);
    mx.x = fmaxf(mx.x, vv.x);
    mx.y = fmaxf(mx.y, vv.y);
    mx.z = fmaxf(mx.z, vv.z);
    mx.w = fmaxf(mx.w, vv.w);
  }
  float4 self = *reinterpret_cast<const float4*>(base + (size_t)n * 256 + oc);
  float4 ph = *reinterpret_cast<const float4*>(Phi_t + ((size_t)b * NN + n) * 256 + oc);
  float4 gg = *reinterpret_cast<const float4*>(g + oc);
  float4 bb = *reinterpret_cast<const float4*>(bt + oc);
  float4 mm = *reinterpret_cast<const float4*>(m + oc);
  float4 vv4 = *reinterpret_cast<const float4*>(v + oc);
  float mxa[4] = {mx.x, mx.y, mx.z, mx.w};
  float sfa[4] = {self.x, self.y, self.z, self.w};
  float pha[4] = {ph.x, ph.y, ph.z, ph.w};
  float ga[4] = {gg.x, gg.y, gg.z, gg.w};
  float ba[4] = {bb.x, bb.y, bb.z, bb.w};
  float ma[4] = {mm.x, mm.y, mm.z, mm.w};
  float va[4] = {vv4.x, vv4.y, vv4.z, vv4.w};
  unsigned short u[4];
  #pragma unroll
  for (int e = 0; e < 4; ++e) {
    float inv = ga[e] / sqrtf(va[e] + EPSV);
    float z = mxa[e] - sfa[e] + pha[e];
    float y = fmaxf(fmaf(z, inv, ba[e] - ma[e] * inv), 0.f);
    u[e] = f2bf(y);
  }
  *reinterpret_cast<uint2*>(&Xb[((size_t)b * NN + n) * 512 + 256 + oc]) =
    *reinterpret_cast<const uint2*>(u);
}

// ---- conv5 via MFMA bf16: A (W-tile) in LDS fragment-major, B in registers
__global__ __launch_bounds__(256, 1) void conv5_mfma_kernel(const unsigned short* __restrict__ Xb,
    const unsigned short* __restrict__ W5b, unsigned* __restrict__ henc) {
  __shared__ __align__(16) unsigned short lA[4096 * 8];
  int b = blockIdx.z;
  int n0 = blockIdx.x * 128, o0 = blockIdx.y * 64;
  int t = threadIdx.x, lane = t & 63, w = t >> 6;
  int r = lane & 15, kc = lane >> 4;

  const unsigned short* B = Xb + ((size_t)b * NN + n0 + w * 32 + r) * 512 + kc * 8;
  bf16x8 b0[16], b1[16];
  #pragma unroll
  for (int ks = 0; ks < 16; ++ks) {
    b0[ks] = *reinterpret_cast<const bf16x8*>(B + ks * 32);
    b1[ks] = *reinterpret_cast<const bf16x8*>(B + 16 * 512 + ks * 32);
  }

  #pragma unroll
  for (int i = 0; i < 16; ++i) {
    int e = i * 256 + t;
    int le = e & 63, je = (e >> 6) & 3, kse = e >> 8;
    const unsigned short* src = W5b + ((size_t)(o0 + je * 16 + (le & 15))) * 512 + ((le >> 4) & 3) * 8 + kse * 32;
    *reinterpret_cast<uint4*>(&lA[(size_t)e * 8]) = *reinterpret_cast<const uint4*>(src);
  }
  __syncthreads();

  f32x4 acc00 = {}, acc01 = {}, acc10 = {}, acc11 = {};
  f32x4 acc20 = {}, acc21 = {}, acc30 = {}, acc31 = {};
  #pragma unroll
  for (int ks = 0; ks < 16; ++ks) {
    bf16x8 a0 = *reinterpret_cast<const bf16x8*>(&lA[(size_t)((ks * 4 + 0) * 64 + lane) * 8]);
    bf16x8 a1 = *reinterpret_cast<const bf16x8*>(&lA[(size_t)((ks * 4 + 1) * 64 + lane) * 8]);
    bf16x8 a2 = *reinterpret_cast<const bf16x8*>(&lA[(size_t)((ks * 4 + 2) * 64 + lane) * 8]);
    bf16x8 a3 = *reinterpret_cast<const bf16x8*>(&lA[(size_t)((ks * 4 + 3) * 64 + lane) * 8]);
    acc00 = __builtin_amdgcn_mfma_f32_16x16x32_bf16(a0, b0[ks], acc00, 0, 0, 0);
    acc01 = __builtin_amdgcn_mfma_f32_16x16x32_bf16(a0, b1[ks], acc01, 0, 0, 0);
    acc10 = __builtin_amdgcn_mfma_f32_16x16x32_bf16(a1, b0[ks], acc10, 0, 0, 0);
    acc11 = __builtin_amdgcn_mfma_f32_16x16x32_bf16(a1, b1[ks], acc11, 0, 0, 0);
    acc20 = __builtin_amdgcn_mfma_f32_16x16x32_bf16(a2, b0[ks], acc20, 0, 0, 0);
    acc21 = __builtin_amdgcn_mfma_f32_16x16x32_bf16(a2, b1[ks], acc21, 0, 0, 0);
    acc30 = __builtin_amdgcn_mfma_f32_16x16x32_bf16(a3, b0[ks], acc30, 0, 0, 0);
    acc31 = __builtin_amdgcn_mfma_f32_16x16x32_bf16(a3, b1[ks], acc31, 0, 0, 0);
  }

  f32x4 m0 = {fmaxf(acc00[0], acc01[0]), fmaxf(acc00[1], acc01[1]),
              fmaxf(acc00[2], acc01[2]), fmaxf(acc00[3], acc01[3])};
  f32x4 m1 = {fmaxf(acc10[0], acc11[0]), fmaxf(acc10[1], acc11[1]),
              fmaxf(acc10[2], acc11[2]), fmaxf(acc10[3], acc11[3])};
  f32x4 m2 = {fmaxf(acc20[0], acc21[0]), fmaxf(acc20[1], acc21[1]),
              fmaxf(acc20[2], acc21[2]), fmaxf(acc20[3], acc21[3])};
  f32x4 m3 = {fmaxf(acc30[0], acc31[0]), fmaxf(acc30[1], acc31[1]),
              fmaxf(acc30[2], acc31[2]), fmaxf(acc30[3], acc31[3])};
  #pragma unroll
  for (int st = 1; st < 16; st <<= 1) {
    #pragma unroll
    for (int reg = 0; reg < 4; ++reg) {
      m0[reg] = fmaxf(m0[reg], __shfl_xor(m0[reg], st));
      m1[reg] = fmaxf(m1[reg], __shfl_xor(m1[reg], st));
      m2[reg] = fmaxf(m2[reg], __shfl_xor(m2[reg], st));
      m3[reg] = fmaxf(m3[reg], __shfl_xor(m3[reg], st));
    }
  }
  if (r == 0) {
    #pragma unroll
    for (int reg = 0; reg < 4; ++reg) {
      atomicMax(&henc[b * 1024 + o0 + 0 * 16 + kc * 4 + reg], fenc(m0[reg]));
      atomicMax(&henc[b * 1024 + o0 + 1 * 16 + kc * 4 + reg], fenc(m1[reg]));
      atomicMax(&henc[b * 1024 + o0 + 2 * 16 + kc * 4 + reg], fenc(m2[reg]));
      atomicMax(&henc[b * 1024 + o0 + 3 * 16 + kc * 4 + reg], fenc(m3[reg]));
    }
  }
}

// ---- FC1
__global__ __launch_bounds__(256) void fc1_kernel(
    const unsigned* __restrict__ henc,
    const float* __restrict__ g5, const float* __restrict__ b5, const float* __restrict__ m5, const float* __restrict__ v5,
    const float* __restrict__ L1W,
    const float* __restrict__ g6, const float* __restrict__ b6, const float* __restrict__ m6, const float* __restrict__ v6,
    float* __restrict__ y1) {
  __shared__ float sh[1024];
  int b = blockIdx.y, t = threadIdx.x;
  int o0 = blockIdx.x * 64;
  for (int o = t; o < 1024; o += 256) {
    float f = fdec(henc[b * 1024 + o]);
    float inv = g5[o] / sqrtf(v5[o] + EPSV);
    sh[o] = fmaxf(fmaf(f, inv, b5[o] - m5[o] * inv), 0.f);
  }
  __syncthreads();
  int o = o0 + (t >> 2), part = t & 3;
  float acc = 0.f;
  const float4* w4 = reinterpret_cast<const float4*>(L1W + (size_t)o * 1024 + part * 256);
  const float4* h4 = reinterpret_cast<const float4*>(sh + part * 256);
  #pragma unroll 8
  for (int c = 0; c < 64; ++c) {
    float4 a = w4[c], q = h4[c];
    acc = fmaf(a.x, q.x, fmaf(a.y, q.y, fmaf(a.z, q.z, fmaf(a.w, q.w, acc))));
  }
  acc += __shfl_xor(acc, 1);
  acc += __shfl_xor(acc, 2);
  if (part == 0) {
    float inv = g6[o] / sqrtf(v6[o] + EPSV);
    y1[b * 512 + o] = fmaxf(fmaf(acc, inv, b6[o] - m6[o] * inv), 0.f);
  }
}

// ---- FC2+FC3
__global__ __launch_bounds__(256) void fc2_kernel(
    const float* __restrict__ y1,
    const float* __restrict__ L2W, const float* __restrict__ L2b,
    const float* __restrict__ g7, const float* __restrict__ b7, const float* __restrict__ m7, const float* __restrict__ v7,
    const float* __restrict__ L3W, const float* __restrict__ L3b,
    float* __restrict__ out) {
  __shared__ float sy1[512];
  __shared__ float sy2[256];
  int b = blockIdx.x, t = threadIdx.x;
  for (int o = t; o < 512; o += 256) sy1[o] = y1[b * 512 + o];
  __syncthreads();
  {
    int o = t;
    float acc = L2b[o];
    const float4* w4 = reinterpret_cast<const float4*>(L2W + (size_t)o * 512);
    const float4* q4 = reinterpret_cast<const float4*>(sy1);
    for (int c = 0; c < 128; ++c) {
      float4 a = w4[c], q = q4[c];
      acc = fmaf(a.x, q.x, fmaf(a.y, q.y, fmaf(a.z, q.z, fmaf(a.w, q.w, acc))));
    }
    float inv = g7[o] / sqrtf(v7[o] + EPSV);
    sy2[o] = fmaxf(fmaf(acc, inv, b7[o] - m7[o] * inv), 0.f);
  }
  __syncthreads();
  if (t < 8) {
    float acc = L3b[t];
    const float4* w4 = reinterpret_cast<const float4*>(L3W + (size_t)t * 256);
    const float4* q4 = reinterpret_cast<const float4*>(sy2);
    for (int c = 0; c < 64; ++c) {
      float4 a = w4[c], q = q4[c];
      acc = fmaf(a.x, q.x, fmaf(a.y, q.y, fmaf(a.z, q.z, fmaf(a.w, q.w, acc))));
    }
    out[b * 8 + t] = acc;
  }
}

extern "C" void kernel_launch(void* const* d_in, const int* in_sizes, int n_in,
                              void* d_out, int out_size, void* d_ws, size_t ws_size,
                              hipStream_t stream) {
  (void)in_sizes; (void)n_in; (void)out_size;
  const float* x   = (const float*)d_in[0];
  const float* W1  = (const float*)d_in[1];
  const float* W2  = (const float*)d_in[2];
  const float* W3  = (const float*)d_in[3];
  const float* W4  = (const float*)d_in[4];
  const float* W5  = (const float*)d_in[5];
  const float* bnp[7][4];
  for (int i = 0; i < 7; ++i)
    for (int j = 0; j < 4; ++j)
      bnp[i][j] = (const float*)d_in[6 + i * 4 + j];
  const float* L1W = (const float*)d_in[34];
  const float* L2W = (const float*)d_in[35];
  const float* L2b = (const float*)d_in[36];
  const float* L3W = (const float*)d_in[37];
  const float* L3b = (const float*)d_in[38];
  float* out = (float*)d_out;

  char* wsb = (char*)d_ws;
  size_t off = 0;
  auto alloc = [&](size_t bytes) -> void* {
    void* p = wsb + off; off += (bytes + 255) & ~(size_t)255; return p;
  };
  int*      idx  = (int*)     alloc((size_t)BB * NN * KK * 4);
  float*    xx   = (float*)   alloc((size_t)BB * NN * 4);
  float*    x1   = (float*)   alloc((size_t)BB * 64  * NN * 4);
  float*    x2   = (float*)   alloc((size_t)BB * 64  * NN * 4);
  float*    x3   = (float*)   alloc((size_t)BB * 128 * NN * 4);
  float*    Plo  = (float*)   alloc((size_t)BB * 256 * NN * 4);
  float*    Phi  = (float*)   alloc((size_t)BB * 256 * NN * 4);
  unsigned* henc = (unsigned*)alloc((size_t)BB * 1024 * 4);
  float*    y1   = (float*)   alloc((size_t)BB * 512 * 4);
  unsigned short* Xb  = (unsigned short*)alloc((size_t)BB * NN * 512 * 2);
  unsigned short* W5b = (unsigned short*)alloc((size_t)1024 * 512 * 2);
  unsigned short* W4b = (unsigned short*)alloc((size_t)256 * 256 * 2);
  size_t left = (ws_size > off) ? (ws_size - off) : 0;
  int nb = 8;
  while (nb > 1 && (size_t)nb * NN * NN * 4 > left) nb >>= 1;
  float* dbuf = (float*)(wsb + off);

  dim3 thr(256);
  #define KNN_PHASE(CIN, XIN)                                                              \
    xx_kernel<CIN><<<dim3(32), thr, 0, stream>>>(XIN, xx);                                 \
    for (int b0 = 0; b0 < BB; b0 += nb) {                                                  \
      dist_kernel<CIN><<<dim3(16, 16, nb), thr, 0, stream>>>(XIN, xx, dbuf, b0);           \
      topk_kernel<<<dim3(NN / 4, nb), thr, 0, stream>>>(dbuf, idx, b0);                    \
    }

  cvtw_kernel<<<dim3(512), thr, 0, stream>>>(W5, W5b);
  cvtw_kernel<<<dim3(64), thr, 0, stream>>>(W4, W4b);

  // ---- level 1: x (C=4) -> x1 (O=64)
  KNN_PHASE(4, x)
  pgemm_kernel<4, 64><<<dim3(16, 1, BB), thr, 0, stream>>>(x, W1, Plo, Phi);
  edgemax_kernel<<<dim3(2, 16, BB), thr, 0, stream>>>(Plo, Phi, idx,
      bnp[0][0], bnp[0][1], bnp[0][2], bnp[0][3], x1, 64);
  tcvt_kernel<<<dim3(16, 1, BB), thr, 0, stream>>>(x1, Xb, 64, 0);
  // ---- level 2: x1 (C=64) -> x2 (O=64)
  KNN_PHASE(64, x1)
  pgemm_kernel<64, 64><<<dim3(16, 1, BB), thr, 0, stream>>>(x1, W2, Plo, Phi);
  edgemax_kernel<<<dim3(2, 16, BB), thr, 0, stream>>>(Plo, Phi, idx,
      bnp[1][0], bnp[1][1], bnp[1][2], bnp[1][3], x2, 64);
  tcvt_kernel<<<dim3(16, 1, BB), thr, 0, stream>>>(x2, Xb, 64, 64);
  // ---- level 3: x2 (C=64) -> x3 (O=128)
  KNN_PHASE(64, x2)
  pgemm_kernel<64, 128><<<dim3(16, 2, BB), thr, 0, stream>>>(x2, W3, Plo, Phi);
  edgemax_kernel<<<dim3(4, 16, BB), thr, 0, stream>>>(Plo, Phi, idx,
      bnp[2][0], bnp[2][1], bnp[2][2], bnp[2][3], x3, 128);
  tcvt_kernel<<<dim3(16, 2, BB), thr, 0, stream>>>(x3, Xb, 128, 128);
  // ---- level 4 (last knn level -> bf16 MFMA end-to-end, n-major)
  KNN_PHASE(128, x3)
  pgemm4_mfma_kernel<<<dim3(8, 4, BB), thr, 0, stream>>>(Xb, W4b, Plo, Phi);
  edgemax4_kernel<<<dim3(256, BB), thr, 0, stream>>>(Plo, Phi, idx,
      bnp[3][0], bnp[3][1], bnp[3][2], bnp[3][3], Xb);
  #undef KNN_PHASE

  // ---- conv5 (MFMA bf16) + global max-pool
  hipMemsetAsync(henc, 0, (size_t)BB * 1024 * 4, stream);
  conv5_mfma_kernel<<<dim3(8, 16, BB), thr, 0, stream>>>(Xb, W5b, henc);

  // ---- FC head
  fc1_kernel<<<dim3(8, BB), thr, 0, stream>>>(henc,
      bnp[4][0], bnp[4][1], bnp[4][2], bnp[4][3], L1W,
      bnp[5][0], bnp[5][1], bnp[5][2], bnp[5][3], y1);
  fc2_kernel<<<dim3(BB), thr, 0, stream>>>(y1,
      L2W, L2b, bnp[6][0], bnp[6][1], bnp[6][2], bnp[6][3], L3W, L3b, out);
}

// Round 19
// 402.059 us; speedup vs baseline: 1.1940x; 1.0358x over previous
//
#include <hip/hip_runtime.h>
#include <cstdint>

#define BB 8
#define NN 1024
#define KK 20
#define EPSV 1e-5f

typedef __attribute__((ext_vector_type(8))) short bf16x8;
typedef __attribute__((ext_vector_type(4))) float f32x4;

__device__ __forceinline__ unsigned fenc(float f) {
  unsigned u = __float_as_uint(f);
  return (u & 0x80000000u) ? ~u : (u | 0x80000000u);
}
__device__ __forceinline__ float fdec(unsigned u) {
  u = (u & 0x80000000u) ? (u & 0x7FFFFFFFu) : ~u;
  return __uint_as_float(u);
}
__device__ __forceinline__ unsigned short f2bf(float f) {
  unsigned u = __float_as_uint(f);
  unsigned r = u + 0x7FFFu + ((u >> 16) & 1u);   // RNE
  return (unsigned short)(r >> 16);
}
__device__ __forceinline__ unsigned mbcnt64(unsigned long long m) {
  unsigned r = __builtin_amdgcn_mbcnt_lo((unsigned)m, 0u);
  return __builtin_amdgcn_mbcnt_hi((unsigned)(m >> 32), r);
}

// ---- per-point squared norm: xx[b*N+n] = sum_c x[b][c][n]^2
template<int C>
__global__ __launch_bounds__(256) void xx_kernel(const float* __restrict__ x, float* __restrict__ xx) {
  int p = blockIdx.x * 256 + threadIdx.x;
  if (p >= BB * NN) return;
  int b = p >> 10, n = p & (NN - 1);
  const float* xb = x + (size_t)b * C * NN + n;
  float s = 0.f;
  #pragma unroll
  for (int c = 0; c < C; ++c) { float t = xb[(size_t)c * NN]; s = fmaf(t, t, s); }
  xx[p] = s;
}

// ---- pairwise d (fp32 EXACT). SYMMETRY-EXPLOITING: only upper-triangle
// tiles (by<=bx) are computed (136 of 256); off-diagonal tiles are mirrored
// via an LDS transpose. Mirror values are bit-identical to what the skipped
// block would compute: fmaf operand swap is exact, accumulation order (c
// ascending, same chunks) identical, epilogue order (2a - xx_row) - xx_col
// preserved. Round-15 lesson: no reg arrays across barriers. Round-17
// lesson: no big-LDS dbuf. smem aliases staging (compute) then transpose.
template<int C>
__global__ __launch_bounds__(256) void dist_kernel(const float* __restrict__ x, const float* __restrict__ xx,
                                                   float* __restrict__ d, int b0) {
  constexpr int CC = (C < 32) ? C : 32;
  constexpr int SM = (2 * CC * 64 > 64 * 65) ? 2 * CC * 64 : 64 * 65;
  __shared__ __align__(16) float smem[SM];
  float* xi = smem;                 // [CC][64]
  float* xj = smem + CC * 64;       // [CC][64]
  int bl = blockIdx.z, b = b0 + bl;
  int qq0 = blockIdx.x;
  int by = 0;
  while (qq0 >= 16 - by) { qq0 -= 16 - by; ++by; }
  int bx = by + qq0;
  int i0 = by * 64, j0 = bx * 64;
  int t = threadIdx.x;
  int tj = t & 15, ti = t >> 4;
  float acc[4][4] = {};
  const float* xb = x + (size_t)b * C * NN;
  for (int c0 = 0; c0 < C; c0 += CC) {
    __syncthreads();
    for (int p = t; p < CC * 16; p += 256) {
      int cc = p >> 4, col = (p & 15) * 4;
      *reinterpret_cast<float4*>(&xi[cc * 64 + col]) =
        *reinterpret_cast<const float4*>(&xb[(size_t)(c0 + cc) * NN + i0 + col]);
      *reinterpret_cast<float4*>(&xj[cc * 64 + col]) =
        *reinterpret_cast<const float4*>(&xb[(size_t)(c0 + cc) * NN + j0 + col]);
    }
    __syncthreads();
    #pragma unroll
    for (int cc = 0; cc < CC; ++cc) {
      float4 A  = *reinterpret_cast<const float4*>(&xi[cc * 64 + ti * 4]);
      float4 Bv = *reinterpret_cast<const float4*>(&xj[cc * 64 + tj * 4]);
      float av[4] = {A.x, A.y, A.z, A.w};
      float bv[4] = {Bv.x, Bv.y, Bv.z, Bv.w};
      #pragma unroll
      for (int a = 0; a < 4; ++a)
        #pragma unroll
        for (int q = 0; q < 4; ++q)
          acc[a][q] = fmaf(av[a], bv[q], acc[a][q]);
    }
  }
  // canonical tile write (identical expression/order to all passing rounds)
  #pragma unroll
  for (int a = 0; a < 4; ++a) {
    int i = i0 + ti * 4 + a;
    float xxi = xx[b * NN + i];
    float4 o;
    o.x = 2.f * acc[a][0] - xxi - xx[b * NN + j0 + tj * 4 + 0];
    o.y = 2.f * acc[a][1] - xxi - xx[b * NN + j0 + tj * 4 + 1];
    o.z = 2.f * acc[a][2] - xxi - xx[b * NN + j0 + tj * 4 + 2];
    o.w = 2.f * acc[a][3] - xxi - xx[b * NN + j0 + tj * 4 + 3];
    *reinterpret_cast<float4*>(&d[((size_t)bl * NN + i) * NN + j0 + tj * 4]) = o;
  }
  // mirror tile (rows at j0, cols at i0) via LDS transpose
  if (by != bx) {
    __syncthreads();   // staging buffer no longer needed; safe to overwrite
    #pragma unroll
    for (int a = 0; a < 4; ++a)
      #pragma unroll
      for (int q = 0; q < 4; ++q)
        smem[(ti * 4 + a) * 65 + tj * 4 + q] = acc[a][q];   // [local_i][local_j]
    __syncthreads();
    #pragma unroll
    for (int a = 0; a < 4; ++a) {
      int jr = j0 + ti * 4 + a;                  // mirror row (original col)
      float xxr = xx[b * NN + jr];
      float4 o;
      o.x = 2.f * smem[(tj * 4 + 0) * 65 + ti * 4 + a] - xxr - xx[b * NN + i0 + tj * 4 + 0];
      o.y = 2.f * smem[(tj * 4 + 1) * 65 + ti * 4 + a] - xxr - xx[b * NN + i0 + tj * 4 + 1];
      o.z = 2.f * smem[(tj * 4 + 2) * 65 + ti * 4 + a] - xxr - xx[b * NN + i0 + tj * 4 + 2];
      o.w = 2.f * smem[(tj * 4 + 3) * 65 + ti * 4 + a] - xxr - xx[b * NN + i0 + tj * 4 + 3];
      *reinterpret_cast<float4*>(&d[((size_t)bl * NN + jr) * NN + i0 + tj * 4]) = o;
    }
  }
}

// ---- top-20 per row via ballot radix-select (set identical to lax.top_k)
__global__ __launch_bounds__(256) void topk_kernel(const float* __restrict__ d, int* __restrict__ idx, int b0) {
  int t = threadIdx.x;
  int wave = t >> 6, lane = t & 63;
  int bl = blockIdx.y, b = b0 + bl;
  int i = blockIdx.x * 4 + wave;
  const float* row = d + ((size_t)bl * NN + i) * NN;

  unsigned v[16];
  #pragma unroll
  for (int p = 0; p < 4; ++p) {
    float4 f = *reinterpret_cast<const float4*>(&row[p * 256 + lane * 4]);
    v[p * 4 + 0] = fenc(f.x);
    v[p * 4 + 1] = fenc(f.y);
    v[p * 4 + 2] = fenc(f.z);
    v[p * 4 + 3] = fenc(f.w);
  }

  unsigned long long lo = 0, hi = 0xFFFFFFFFull;
  while (lo < hi) {
    unsigned long long mid = lo + ((hi - lo + 1) >> 1);
    unsigned mt = (unsigned)mid;
    int c = 0;
    #pragma unroll
    for (int e = 0; e < 16; ++e)
      c += __popcll(__ballot(v[e] >= mt));
    if (c >= KK) lo = mid; else hi = mid - 1;
  }
  unsigned T = (unsigned)lo;

  int* op = idx + ((size_t)b * NN + i) * KK;
  int base = 0, n1 = 0;
  #pragma unroll
  for (int e = 0; e < 16; ++e) {
    unsigned long long mask = __ballot(v[e] > T);
    unsigned mb = mbcnt64(mask);
    if (v[e] > T) op[base + mb] = (e >> 2) * 256 + lane * 4 + (e & 3);
    base += __popcll(mask);
  }
  n1 = base;
  int need = KK - n1;
  int neq = 0;
  #pragma unroll
  for (int e = 0; e < 16; ++e) neq += __popcll(__ballot(v[e] == T));
  if (neq == need) {
    #pragma unroll
    for (int e = 0; e < 16; ++e) {
      unsigned long long mask = __ballot(v[e] == T);
      unsigned mb = mbcnt64(mask);
      if (v[e] == T) op[base + mb] = (e >> 2) * 256 + lane * 4 + (e & 3);
      base += __popcll(mask);
    }
  } else {
    unsigned taken = 0;
    for (int s = 0; s < need; ++s) {
      int jm = 1 << 30;
      #pragma unroll
      for (int e = 0; e < 16; ++e) {
        if (v[e] == T && !((taken >> e) & 1u)) {
          int j = (e >> 2) * 256 + lane * 4 + (e & 3);
          jm = jm < j ? jm : j;
        }
      }
      #pragma unroll
      for (int st = 1; st < 64; st <<= 1) {
        int oj = __shfl_xor(jm, st);
        jm = jm < oj ? jm : oj;
      }
      if (lane == ((jm >> 2) & 63)) {
        int e = (((jm >> 8) << 2) | (jm & 3));
        taken |= 1u << e;
        op[base + s] = jm;
      }
    }
  }
}

// ---- P_lo/P_hi fp32 GEMM (levels 1-3; outputs feed later knn, keep fp32)
template<int C, int O>
__global__ __launch_bounds__(256) void pgemm_kernel(const float* __restrict__ x, const float* __restrict__ W,
                                                    float* __restrict__ Plo, float* __restrict__ Phi) {
  constexpr int CC = (C < 64) ? C : 64;
  __shared__ __align__(16) float xs[CC][64];
  __shared__ __align__(16) float wls[CC][68];
  __shared__ __align__(16) float whs[CC][68];
  int b = blockIdx.z;
  int o0 = blockIdx.y * 64, n0 = blockIdx.x * 64;
  int t = threadIdx.x;
  int tn = t & 15, to = t >> 4;
  float accl[4][4] = {}, acch[4][4] = {};
  const float* xb = x + (size_t)b * C * NN;
  for (int c0 = 0; c0 < C; c0 += CC) {
    __syncthreads();
    for (int p = t; p < CC * 64; p += 256) {
      int cc = p >> 6, col = p & 63;
      xs[cc][col] = xb[(size_t)(c0 + cc) * NN + n0 + col];
    }
    for (int p = t; p < 64 * CC; p += 256) {
      int ol = p / CC, cc = p % CC;
      wls[cc][ol] = W[(size_t)(o0 + ol) * (2 * C) + c0 + cc];
      whs[cc][ol] = W[(size_t)(o0 + ol) * (2 * C) + C + c0 + cc];
    }
    __syncthreads();
    #pragma unroll
    for (int cc = 0; cc < CC; ++cc) {
      float4 X  = *reinterpret_cast<const float4*>(&xs[cc][tn * 4]);
      float4 Wl = *reinterpret_cast<const float4*>(&wls[cc][to * 4]);
      float4 Wh = *reinterpret_cast<const float4*>(&whs[cc][to * 4]);
      float xv[4] = {X.x, X.y, X.z, X.w};
      float wl[4] = {Wl.x, Wl.y, Wl.z, Wl.w};
      float wh[4] = {Wh.x, Wh.y, Wh.z, Wh.w};
      #pragma unroll
      for (int a = 0; a < 4; ++a)
        #pragma unroll
        for (int q = 0; q < 4; ++q) {
          accl[a][q] = fmaf(wl[a], xv[q], accl[a][q]);
          acch[a][q] = fmaf(wh[a], xv[q], acch[a][q]);
        }
    }
  }
  #pragma unroll
  for (int a = 0; a < 4; ++a) {
    int o = o0 + to * 4 + a;
    size_t base = ((size_t)b * O + o) * NN + n0 + tn * 4;
    float4 vl = {accl[a][0], accl[a][1], accl[a][2], accl[a][3]};
    float4 vh = {acch[a][0], acch[a][1], acch[a][2], acch[a][3]};
    *reinterpret_cast<float4*>(&Plo[base]) = vl;
    *reinterpret_cast<float4*>(&Phi[base]) = vh;
  }
}

// ---- edge max (levels 1-3): four rows per iteration
__global__ __launch_bounds__(256) void edgemax_kernel(const float* __restrict__ Plo, const float* __restrict__ Phi,
    const int* __restrict__ idx, const float* __restrict__ g, const float* __restrict__ bt,
    const float* __restrict__ m, const float* __restrict__ v,
    float* __restrict__ xout, int O) {
  __shared__ __align__(16) float srow[4][NN];
  __shared__ __align__(16) float sphi[4][64];
  __shared__ int   sidx[64 * KK];
  __shared__ float sinv[32], ssb[32];
  int b = blockIdx.z, n0 = blockIdx.y * 64, o0 = blockIdx.x * 32;
  int t = threadIdx.x;
  if (t < 32) {
    float inv = g[o0 + t] / sqrtf(v[o0 + t] + EPSV);
    sinv[t] = inv; ssb[t] = bt[o0 + t] - m[o0 + t] * inv;
  }
  for (int p = t; p < 64 * KK; p += 256) sidx[p] = idx[((size_t)b * NN + n0) * KK + p];
  const float* plobase = Plo + (size_t)b * O * NN;
  const float* phibase = Phi + (size_t)b * O * NN;
  float4 cur0 = *reinterpret_cast<const float4*>(&plobase[(size_t)(o0 + 0) * NN + t * 4]);
  float4 cur1 = *reinterpret_cast<const float4*>(&plobase[(size_t)(o0 + 1) * NN + t * 4]);
  float4 cur2 = *reinterpret_cast<const float4*>(&plobase[(size_t)(o0 + 2) * NN + t * 4]);
  float4 cur3 = *reinterpret_cast<const float4*>(&plobase[(size_t)(o0 + 3) * NN + t * 4]);
  float4 curphi;
  if (t < 64) curphi = *reinterpret_cast<const float4*>(&phibase[(size_t)(o0 + (t >> 4)) * NN + n0 + (t & 15) * 4]);
  __syncthreads();
  int n = t >> 2, kg = t & 3;
  int j0 = sidx[n * KK + kg * 5 + 0];
  int j1 = sidx[n * KK + kg * 5 + 1];
  int j2 = sidx[n * KK + kg * 5 + 2];
  int j3 = sidx[n * KK + kg * 5 + 3];
  int j4 = sidx[n * KK + kg * 5 + 4];
  for (int oo = 0; oo < 32; oo += 4) {
    *reinterpret_cast<float4*>(&srow[0][t * 4]) = cur0;
    *reinterpret_cast<float4*>(&srow[1][t * 4]) = cur1;
    *reinterpret_cast<float4*>(&srow[2][t * 4]) = cur2;
    *reinterpret_cast<float4*>(&srow[3][t * 4]) = cur3;
    if (t < 64) *reinterpret_cast<float4*>(&sphi[t >> 4][(t & 15) * 4]) = curphi;
    if (oo < 28) {
      cur0 = *reinterpret_cast<const float4*>(&plobase[(size_t)(o0 + oo + 4) * NN + t * 4]);
      cur1 = *reinterpret_cast<const float4*>(&plobase[(size_t)(o0 + oo + 5) * NN + t * 4]);
      cur2 = *reinterpret_cast<const float4*>(&plobase[(size_t)(o0 + oo + 6) * NN + t * 4]);
      cur3 = *reinterpret_cast<const float4*>(&plobase[(size_t)(o0 + oo + 7) * NN + t * 4]);
      if (t < 64) curphi = *reinterpret_cast<const float4*>(&phibase[(size_t)(o0 + oo + 4 + (t >> 4)) * NN + n0 + (t & 15) * 4]);
    }
    __syncthreads();
    #pragma unroll
    for (int r = 0; r < 4; ++r) {
      float mx = srow[r][j0];
      mx = fmaxf(mx, srow[r][j1]);
      mx = fmaxf(mx, srow[r][j2]);
      mx = fmaxf(mx, srow[r][j3]);
      mx = fmaxf(mx, srow[r][j4]);
      mx = fmaxf(mx, __shfl_xor(mx, 1));
      mx = fmaxf(mx, __shfl_xor(mx, 2));
      if (kg == 0) {
        float z = mx - srow[r][n0 + n] + sphi[r][n];
        xout[((size_t)b * O + o0 + oo + r) * NN + n0 + n] =
          fmaxf(fmaf(z, sinv[oo + r], ssb[oo + r]), 0.f);
      }
    }
    __syncthreads();
  }
}

// ---- transpose+cvt: src fp32 [b][Csrc][NN] -> dst bf16 Xb[b][NN][512] at col c0
__global__ __launch_bounds__(256) void tcvt_kernel(const float* __restrict__ src,
    unsigned short* __restrict__ dst, int Csrc, int c0) {
  __shared__ float tile[64][65];
  int b = blockIdx.z, cb = blockIdx.y * 64, n0 = blockIdx.x * 64;
  int t = threadIdx.x;
  const float* s = src + ((size_t)b * Csrc + cb) * NN + n0;
  #pragma unroll
  for (int rr = 0; rr < 4; ++rr) {
    int r = (t >> 4) + rr * 16;
    float4 v = *reinterpret_cast<const float4*>(&s[(size_t)r * NN + (t & 15) * 4]);
    tile[r][(t & 15) * 4 + 0] = v.x;
    tile[r][(t & 15) * 4 + 1] = v.y;
    tile[r][(t & 15) * 4 + 2] = v.z;
    tile[r][(t & 15) * 4 + 3] = v.w;
  }
  __syncthreads();
  #pragma unroll
  for (int rr = 0; rr < 2; ++rr) {
    int chunk = t + 256 * rr;
    int n = chunk >> 3, cg = (chunk & 7) * 8;
    unsigned short u[8];
    #pragma unroll
    for (int j = 0; j < 8; ++j) u[j] = f2bf(tile[cg + j][n]);
    *reinterpret_cast<uint4*>(&dst[((size_t)b * NN + n0 + n) * 512 + c0 + cb + cg]) =
      *reinterpret_cast<const uint4*>(u);
  }
}

// ---- fp32 -> bf16 elementwise (weights)
__global__ __launch_bounds__(256) void cvtw_kernel(const float* __restrict__ W, unsigned short* __restrict__ Wb) {
  int p = (blockIdx.x * 256 + threadIdx.x) * 4;
  float4 v = *reinterpret_cast<const float4*>(&W[p]);
  unsigned short u[4] = {f2bf(v.x), f2bf(v.y), f2bf(v.z), f2bf(v.w)};
  *reinterpret_cast<uint2*>(&Wb[p]) = *reinterpret_cast<const uint2*>(u);
}

// ---- pgemm L4 via MFMA bf16, SWAPPED operands; n-major Plo_t/Phi_t output
__global__ __launch_bounds__(256) void pgemm4_mfma_kernel(const unsigned short* __restrict__ Xb,
    const unsigned short* __restrict__ W4b, float* __restrict__ Plo_t, float* __restrict__ Phi_t) {
  int b = blockIdx.z;
  int n0 = blockIdx.x * 128, o0 = blockIdx.y * 64;
  int t = threadIdx.x, lane = t & 63, w = t >> 6;
  int r = lane & 15, kc = lane >> 4;
  const unsigned short* A  = Xb + ((size_t)b * NN + n0 + w * 32 + r) * 512 + 128 + kc * 8;
  const unsigned short* Bw = W4b + ((size_t)(o0 + r)) * 256 + kc * 8;
  f32x4 accl0[4] = {}, accl1[4] = {}, acch0[4] = {}, acch1[4] = {};
  #pragma unroll
  for (int ks = 0; ks < 128; ks += 32) {
    bf16x8 a0 = *reinterpret_cast<const bf16x8*>(A + ks);
    bf16x8 a1 = *reinterpret_cast<const bf16x8*>(A + 16 * 512 + ks);
    #pragma unroll
    for (int j = 0; j < 4; ++j) {
      bf16x8 bl = *reinterpret_cast<const bf16x8*>(Bw + (size_t)j * 16 * 256 + ks);
      bf16x8 bh = *reinterpret_cast<const bf16x8*>(Bw + (size_t)j * 16 * 256 + 128 + ks);
      accl0[j] = __builtin_amdgcn_mfma_f32_16x16x32_bf16(a0, bl, accl0[j], 0, 0, 0);
      accl1[j] = __builtin_amdgcn_mfma_f32_16x16x32_bf16(a1, bl, accl1[j], 0, 0, 0);
      acch0[j] = __builtin_amdgcn_mfma_f32_16x16x32_bf16(a0, bh, acch0[j], 0, 0, 0);
      acch1[j] = __builtin_amdgcn_mfma_f32_16x16x32_bf16(a1, bh, acch1[j], 0, 0, 0);
    }
  }
  #pragma unroll
  for (int j = 0; j < 4; ++j) {
    #pragma unroll
    for (int reg = 0; reg < 4; ++reg) {
      size_t n_a = (size_t)b * NN + n0 + w * 32 + kc * 4 + reg;
      size_t n_b = n_a + 16;
      int oc = o0 + j * 16 + r;
      Plo_t[n_a * 256 + oc] = accl0[j][reg];
      Plo_t[n_b * 256 + oc] = accl1[j][reg];
      Phi_t[n_a * 256 + oc] = acch0[j][reg];
      Phi_t[n_b * 256 + oc] = acch1[j][reg];
    }
  }
}

// ---- edge max L4 (n-major): zero LDS/barriers, coalesced gathers, bf16 out
__global__ __launch_bounds__(256) void edgemax4_kernel(const float* __restrict__ Plo_t,
    const float* __restrict__ Phi_t, const int* __restrict__ idx,
    const float* __restrict__ g, const float* __restrict__ bt,
    const float* __restrict__ m, const float* __restrict__ v,
    unsigned short* __restrict__ Xb) {
  int b = blockIdx.y, t = threadIdx.x;
  int n = blockIdx.x * 4 + (t >> 6);
  int oc = (t & 63) * 4;
  const int* ip = idx + ((size_t)b * NN + n) * KK;
  const float* base = Plo_t + (size_t)b * NN * 256;
  float4 mx = {-3.4e38f, -3.4e38f, -3.4e38f, -3.4e38f};
  #pragma unroll
  for (int k = 0; k < KK; ++k) {
    float4 vv = *reinterpret_cast<const float4*>(base + (size_t)ip[k] * 256 + oc);
    mx.x = fmaxf(mx.x, vv.x);
    mx.y = fmaxf(mx.y, vv.y);
    mx.z = fmaxf(mx.z, vv.z);
    mx.w = fmaxf(mx.w, vv.w);
  }
  float4 self = *reinterpret_cast<const float4*>(base + (size_t)n * 256 + oc);
  float4 ph = *reinterpret_cast<const float4*>(Phi_t + ((size_t)b * NN + n) * 256 + oc);
  float4 gg = *reinterpret_cast<const float4*>(g + oc);
  float4 bb = *reinterpret_cast<const float4*>(bt + oc);
  float4 mm = *reinterpret_cast<const float4*>(m + oc);
  float4 vv4 = *reinterpret_cast<const float4*>(v + oc);
  float mxa[4] = {mx.x, mx.y, mx.z, mx.w};
  float sfa[4] = {self.x, self.y, self.z, self.w};
  float pha[4] = {ph.x, ph.y, ph.z, ph.w};
  float ga[4] = {gg.x, gg.y, gg.z, gg.w};
  float ba[4] = {bb.x, bb.y, bb.z, bb.w};
  float ma[4] = {mm.x, mm.y, mm.z, mm.w};
  float va[4] = {vv4.x, vv4.y, vv4.z, vv4.w};
  unsigned short u[4];
  #pragma unroll
  for (int e = 0; e < 4; ++e) {
    float inv = ga[e] / sqrtf(va[e] + EPSV);
    float z = mxa[e] - sfa[e] + pha[e];
    float y = fmaxf(fmaf(z, inv, ba[e] - ma[e] * inv), 0.f);
    u[e] = f2bf(y);
  }
  *reinterpret_cast<uint2*>(&Xb[((size_t)b * NN + n) * 512 + 256 + oc]) =
    *reinterpret_cast<const uint2*>(u);
}

// ---- conv5 via MFMA bf16: A (W-tile) in LDS fragment-major, B in registers
__global__ __launch_bounds__(256, 1) void conv5_mfma_kernel(const unsigned short* __restrict__ Xb,
    const unsigned short* __restrict__ W5b, unsigned* __restrict__ henc) {
  __shared__ __align__(16) unsigned short lA[4096 * 8];
  int b = blockIdx.z;
  int n0 = blockIdx.x * 128, o0 = blockIdx.y * 64;
  int t = threadIdx.x, lane = t & 63, w = t >> 6;
  int r = lane & 15, kc = lane >> 4;

  const unsigned short* B = Xb + ((size_t)b * NN + n0 + w * 32 + r) * 512 + kc * 8;
  bf16x8 b0[16], b1[16];
  #pragma unroll
  for (int ks = 0; ks < 16; ++ks) {
    b0[ks] = *reinterpret_cast<const bf16x8*>(B + ks * 32);
    b1[ks] = *reinterpret_cast<const bf16x8*>(B + 16 * 512 + ks * 32);
  }

  #pragma unroll
  for (int i = 0; i < 16; ++i) {
    int e = i * 256 + t;
    int le = e & 63, je = (e >> 6) & 3, kse = e >> 8;
    const unsigned short* src = W5b + ((size_t)(o0 + je * 16 + (le & 15))) * 512 + ((le >> 4) & 3) * 8 + kse * 32;
    *reinterpret_cast<uint4*>(&lA[(size_t)e * 8]) = *reinterpret_cast<const uint4*>(src);
  }
  __syncthreads();

  f32x4 acc00 = {}, acc01 = {}, acc10 = {}, acc11 = {};
  f32x4 acc20 = {}, acc21 = {}, acc30 = {}, acc31 = {};
  #pragma unroll
  for (int ks = 0; ks < 16; ++ks) {
    bf16x8 a0 = *reinterpret_cast<const bf16x8*>(&lA[(size_t)((ks * 4 + 0) * 64 + lane) * 8]);
    bf16x8 a1 = *reinterpret_cast<const bf16x8*>(&lA[(size_t)((ks * 4 + 1) * 64 + lane) * 8]);
    bf16x8 a2 = *reinterpret_cast<const bf16x8*>(&lA[(size_t)((ks * 4 + 2) * 64 + lane) * 8]);
    bf16x8 a3 = *reinterpret_cast<const bf16x8*>(&lA[(size_t)((ks * 4 + 3) * 64 + lane) * 8]);
    acc00 = __builtin_amdgcn_mfma_f32_16x16x32_bf16(a0, b0[ks], acc00, 0, 0, 0);
    acc01 = __builtin_amdgcn_mfma_f32_16x16x32_bf16(a0, b1[ks], acc01, 0, 0, 0);
    acc10 = __builtin_amdgcn_mfma_f32_16x16x32_bf16(a1, b0[ks], acc10, 0, 0, 0);
    acc11 = __builtin_amdgcn_mfma_f32_16x16x32_bf16(a1, b1[ks], acc11, 0, 0, 0);
    acc20 = __builtin_amdgcn_mfma_f32_16x16x32_bf16(a2, b0[ks], acc20, 0, 0, 0);
    acc21 = __builtin_amdgcn_mfma_f32_16x16x32_bf16(a2, b1[ks], acc21, 0, 0, 0);
    acc30 = __builtin_amdgcn_mfma_f32_16x16x32_bf16(a3, b0[ks], acc30, 0, 0, 0);
    acc31 = __builtin_amdgcn_mfma_f32_16x16x32_bf16(a3, b1[ks], acc31, 0, 0, 0);
  }

  f32x4 m0 = {fmaxf(acc00[0], acc01[0]), fmaxf(acc00[1], acc01[1]),
              fmaxf(acc00[2], acc01[2]), fmaxf(acc00[3], acc01[3])};
  f32x4 m1 = {fmaxf(acc10[0], acc11[0]), fmaxf(acc10[1], acc11[1]),
              fmaxf(acc10[2], acc11[2]), fmaxf(acc10[3], acc11[3])};
  f32x4 m2 = {fmaxf(acc20[0], acc21[0]), fmaxf(acc20[1], acc21[1]),
              fmaxf(acc20[2], acc21[2]), fmaxf(acc20[3], acc21[3])};
  f32x4 m3 = {fmaxf(acc30[0], acc31[0]), fmaxf(acc30[1], acc31[1]),
              fmaxf(acc30[2], acc31[2]), fmaxf(acc30[3], acc31[3])};
  #pragma unroll
  for (int st = 1; st < 16; st <<= 1) {
    #pragma unroll
    for (int reg = 0; reg < 4; ++reg) {
      m0[reg] = fmaxf(m0[reg], __shfl_xor(m0[reg], st));
      m1[reg] = fmaxf(m1[reg], __shfl_xor(m1[reg], st));
      m2[reg] = fmaxf(m2[reg], __shfl_xor(m2[reg], st));
      m3[reg] = fmaxf(m3[reg], __shfl_xor(m3[reg], st));
    }
  }
  if (r == 0) {
    #pragma unroll
    for (int reg = 0; reg < 4; ++reg) {
      atomicMax(&henc[b * 1024 + o0 + 0 * 16 + kc * 4 + reg], fenc(m0[reg]));
      atomicMax(&henc[b * 1024 + o0 + 1 * 16 + kc * 4 + reg], fenc(m1[reg]));
      atomicMax(&henc[b * 1024 + o0 + 2 * 16 + kc * 4 + reg], fenc(m2[reg]));
      atomicMax(&henc[b * 1024 + o0 + 3 * 16 + kc * 4 + reg], fenc(m3[reg]));
    }
  }
}

// ---- FC1
__global__ __launch_bounds__(256) void fc1_kernel(
    const unsigned* __restrict__ henc,
    const float* __restrict__ g5, const float* __restrict__ b5, const float* __restrict__ m5, const float* __restrict__ v5,
    const float* __restrict__ L1W,
    const float* __restrict__ g6, const float* __restrict__ b6, const float* __restrict__ m6, const float* __restrict__ v6,
    float* __restrict__ y1) {
  __shared__ float sh[1024];
  int b = blockIdx.y, t = threadIdx.x;
  int o0 = blockIdx.x * 64;
  for (int o = t; o < 1024; o += 256) {
    float f = fdec(henc[b * 1024 + o]);
    float inv = g5[o] / sqrtf(v5[o] + EPSV);
    sh[o] = fmaxf(fmaf(f, inv, b5[o] - m5[o] * inv), 0.f);
  }
  __syncthreads();
  int o = o0 + (t >> 2), part = t & 3;
  float acc = 0.f;
  const float4* w4 = reinterpret_cast<const float4*>(L1W + (size_t)o * 1024 + part * 256);
  const float4* h4 = reinterpret_cast<const float4*>(sh + part * 256);
  #pragma unroll 8
  for (int c = 0; c < 64; ++c) {
    float4 a = w4[c], q = h4[c];
    acc = fmaf(a.x, q.x, fmaf(a.y, q.y, fmaf(a.z, q.z, fmaf(a.w, q.w, acc))));
  }
  acc += __shfl_xor(acc, 1);
  acc += __shfl_xor(acc, 2);
  if (part == 0) {
    float inv = g6[o] / sqrtf(v6[o] + EPSV);
    y1[b * 512 + o] = fmaxf(fmaf(acc, inv, b6[o] - m6[o] * inv), 0.f);
  }
}

// ---- FC2+FC3
__global__ __launch_bounds__(256) void fc2_kernel(
    const float* __restrict__ y1,
    const float* __restrict__ L2W, const float* __restrict__ L2b,
    const float* __restrict__ g7, const float* __restrict__ b7, const float* __restrict__ m7, const float* __restrict__ v7,
    const float* __restrict__ L3W, const float* __restrict__ L3b,
    float* __restrict__ out) {
  __shared__ float sy1[512];
  __shared__ float sy2[256];
  int b = blockIdx.x, t = threadIdx.x;
  for (int o = t; o < 512; o += 256) sy1[o] = y1[b * 512 + o];
  __syncthreads();
  {
    int o = t;
    float acc = L2b[o];
    const float4* w4 = reinterpret_cast<const float4*>(L2W + (size_t)o * 512);
    const float4* q4 = reinterpret_cast<const float4*>(sy1);
    for (int c = 0; c < 128; ++c) {
      float4 a = w4[c], q = q4[c];
      acc = fmaf(a.x, q.x, fmaf(a.y, q.y, fmaf(a.z, q.z, fmaf(a.w, q.w, acc))));
    }
    float inv = g7[o] / sqrtf(v7[o] + EPSV);
    sy2[o] = fmaxf(fmaf(acc, inv, b7[o] - m7[o] * inv), 0.f);
  }
  __syncthreads();
  if (t < 8) {
    float acc = L3b[t];
    const float4* w4 = reinterpret_cast<const float4*>(L3W + (size_t)t * 256);
    const float4* q4 = reinterpret_cast<const float4*>(sy2);
    for (int c = 0; c < 64; ++c) {
      float4 a = w4[c], q = q4[c];
      acc = fmaf(a.x, q.x, fmaf(a.y, q.y, fmaf(a.z, q.z, fmaf(a.w, q.w, acc))));
    }
    out[b * 8 + t] = acc;
  }
}

extern "C" void kernel_launch(void* const* d_in, const int* in_sizes, int n_in,
                              void* d_out, int out_size, void* d_ws, size_t ws_size,
                              hipStream_t stream) {
  (void)in_sizes; (void)n_in; (void)out_size;
  const float* x   = (const float*)d_in[0];
  const float* W1  = (const float*)d_in[1];
  const float* W2  = (const float*)d_in[2];
  const float* W3  = (const float*)d_in[3];
  const float* W4  = (const float*)d_in[4];
  const float* W5  = (const float*)d_in[5];
  const float* bnp[7][4];
  for (int i = 0; i < 7; ++i)
    for (int j = 0; j < 4; ++j)
      bnp[i][j] = (const float*)d_in[6 + i * 4 + j];
  const float* L1W = (const float*)d_in[34];
  const float* L2W = (const float*)d_in[35];
  const float* L2b = (const float*)d_in[36];
  const float* L3W = (const float*)d_in[37];
  const float* L3b = (const float*)d_in[38];
  float* out = (float*)d_out;

  char* wsb = (char*)d_ws;
  size_t off = 0;
  auto alloc = [&](size_t bytes) -> void* {
    void* p = wsb + off; off += (bytes + 255) & ~(size_t)255; return p;
  };
  int*      idx  = (int*)     alloc((size_t)BB * NN * KK * 4);
  float*    xx   = (float*)   alloc((size_t)BB * NN * 4);
  float*    x1   = (float*)   alloc((size_t)BB * 64  * NN * 4);
  float*    x2   = (float*)   alloc((size_t)BB * 64  * NN * 4);
  float*    x3   = (float*)   alloc((size_t)BB * 128 * NN * 4);
  float*    Plo  = (float*)   alloc((size_t)BB * 256 * NN * 4);
  float*    Phi  = (float*)   alloc((size_t)BB * 256 * NN * 4);
  unsigned* henc = (unsigned*)alloc((size_t)BB * 1024 * 4);
  float*    y1   = (float*)   alloc((size_t)BB * 512 * 4);
  unsigned short* Xb  = (unsigned short*)alloc((size_t)BB * NN * 512 * 2);
  unsigned short* W5b = (unsigned short*)alloc((size_t)1024 * 512 * 2);
  unsigned short* W4b = (unsigned short*)alloc((size_t)256 * 256 * 2);
  size_t left = (ws_size > off) ? (ws_size - off) : 0;
  int nb = 8;
  while (nb > 1 && (size_t)nb * NN * NN * 4 > left) nb >>= 1;
  float* dbuf = (float*)(wsb + off);

  dim3 thr(256);
  #define KNN_PHASE(CIN, XIN)                                                              \
    xx_kernel<CIN><<<dim3(32), thr, 0, stream>>>(XIN, xx);                                 \
    for (int b0 = 0; b0 < BB; b0 += nb) {                                                  \
      dist_kernel<CIN><<<dim3(136, 1, nb), thr, 0, stream>>>(XIN, xx, dbuf, b0);           \
      topk_kernel<<<dim3(NN / 4, nb), thr, 0, stream>>>(dbuf, idx, b0);                    \
    }

  cvtw_kernel<<<dim3(512), thr, 0, stream>>>(W5, W5b);
  cvtw_kernel<<<dim3(64), thr, 0, stream>>>(W4, W4b);

  // ---- level 1: x (C=4) -> x1 (O=64)
  KNN_PHASE(4, x)
  pgemm_kernel<4, 64><<<dim3(16, 1, BB), thr, 0, stream>>>(x, W1, Plo, Phi);
  edgemax_kernel<<<dim3(2, 16, BB), thr, 0, stream>>>(Plo, Phi, idx,
      bnp[0][0], bnp[0][1], bnp[0][2], bnp[0][3], x1, 64);
  tcvt_kernel<<<dim3(16, 1, BB), thr, 0, stream>>>(x1, Xb, 64, 0);
  // ---- level 2: x1 (C=64) -> x2 (O=64)
  KNN_PHASE(64, x1)
  pgemm_kernel<64, 64><<<dim3(16, 1, BB), thr, 0, stream>>>(x1, W2, Plo, Phi);
  edgemax_kernel<<<dim3(2, 16, BB), thr, 0, stream>>>(Plo, Phi, idx,
      bnp[1][0], bnp[1][1], bnp[1][2], bnp[1][3], x2, 64);
  tcvt_kernel<<<dim3(16, 1, BB), thr, 0, stream>>>(x2, Xb, 64, 64);
  // ---- level 3: x2 (C=64) -> x3 (O=128)
  KNN_PHASE(64, x2)
  pgemm_kernel<64, 128><<<dim3(16, 2, BB), thr, 0, stream>>>(x2, W3, Plo, Phi);
  edgemax_kernel<<<dim3(4, 16, BB), thr, 0, stream>>>(Plo, Phi, idx,
      bnp[2][0], bnp[2][1], bnp[2][2], bnp[2][3], x3, 128);
  tcvt_kernel<<<dim3(16, 2, BB), thr, 0, stream>>>(x3, Xb, 128, 128);
  // ---- level 4 (last knn level -> bf16 MFMA end-to-end, n-major)
  KNN_PHASE(128, x3)
  pgemm4_mfma_kernel<<<dim3(8, 4, BB), thr, 0, stream>>>(Xb, W4b, Plo, Phi);
  edgemax4_kernel<<<dim3(256, BB), thr, 0, stream>>>(Plo, Phi, idx,
      bnp[3][0], bnp[3][1], bnp[3][2], bnp[3][3], Xb);
  #undef KNN_PHASE

  // ---- conv5 (MFMA bf16) + global max-pool
  hipMemsetAsync(henc, 0, (size_t)BB * 1024 * 4, stream);
  conv5_mfma_kernel<<<dim3(8, 16, BB), thr, 0, stream>>>(Xb, W5b, henc);

  // ---- FC head
  fc1_kernel<<<dim3(8, BB), thr, 0, stream>>>(henc,
      bnp[4][0], bnp[4][1], bnp[4][2], bnp[4][3], L1W,
      bnp[5][0], bnp[5][1], bnp[5][2], bnp[5][3], y1);
  fc2_kernel<<<dim3(BB), thr, 0, stream>>>(y1,
      L2W, L2b, bnp[6][0], bnp[6][1], bnp[6][2], bnp[6][3], L3W, L3b, out);
}